// Round 5
// baseline (2200.095 us; speedup 1.0000x reference)
//
#include <hip/hip_runtime.h>
#include <math.h>

#define EPSI 1e-5f

// ---------------- workspace layout (floats) ----------------
//   A1[96] @0, C1[32] @96, A2[1024] @128, C2[32] @1152,
//   sa[32] @1184, Ca[32] @1216, sb[32] @1248, Cb[32] @1280,
//   fs1[64] @1312, fc1[64] @1376, fs2[64] @1440, fc2[64] @1504
#define P_D1 2048                    // 128*83*83 = 881792
#define P_D2 (P_D1 + 128*83*83)
#define P_D3 (P_D2 + 128*28*28)
#define P_D4 (P_D3 + 128*10*10)
#define P_D5 (P_D4 + 128*4*4)
#define P_SCORE (P_D5 + 128*2*2)     // 4*64*256*256 = 16777216 floats
#define P_D  P_SCORE                 // d (4,32,248,248) aliases score head (dead before accum)

__device__ __forceinline__ float rfl(float x) {
  return __builtin_bit_cast(float, __builtin_amdgcn_readfirstlane(__builtin_bit_cast(int, x)));
}

struct PrepArgs { const float* p[39]; };

// ---------------- prep: fold all affine params ----------------
__global__ void k_prep(PrepArgs a, float* __restrict__ P) {
  int t = threadIdx.x;
  const float *w1=a.p[1],*b1=a.p[2],*w2=a.p[3],*b2=a.p[4],*g1=a.p[5],*bb1=a.p[6],*m1=a.p[7],*v1=a.p[8];
  const float *w3=a.p[9],*b3=a.p[10],*w4=a.p[11],*b4=a.p[12],*g2=a.p[13],*bb2=a.p[14],*m2=a.p[15],*v2=a.p[16];
  for (int i=t;i<96;i+=256){ int o=i/3; float s=g1[o]/sqrtf(v1[o]+EPSI); P[i]=w1[i]*w2[o]*s; }
  for (int o=t;o<32;o+=256){ float s=g1[o]/sqrtf(v1[o]+EPSI); P[96+o]=(b1[o]*w2[o]+b2[o]-m1[o])*s+bb1[o]; }
  for (int i=t;i<1024;i+=256){ int o2=i/32; float s=g2[o2]/sqrtf(v2[o2]+EPSI); P[128+i]=w3[i]*w4[o2]*s; }
  for (int o=t;o<32;o+=256){ float s=g2[o]/sqrtf(v2[o]+EPSI); P[1152+o]=(b3[o]*w4[o]+b4[o]-m2[o])*s+bb2[o]; }
  const float *iag=a.p[21],*iab=a.p[22],*iam=a.p[23],*iav=a.p[24],*iabias=a.p[20];
  for (int c=t;c<32;c+=256){ float s=iag[c]/sqrtf(iav[c]+EPSI); P[1184+c]=s; P[1216+c]=(iabias[0]-iam[c])*s+iab[c]; }
  const float *ibg=a.p[27],*ibb=a.p[28],*ibm=a.p[29],*ibv=a.p[30],*ibbias=a.p[26];
  for (int c=t;c<32;c+=256){ float s=ibg[c]/sqrtf(ibv[c]+EPSI); P[1248+c]=s; P[1280+c]=(ibbias[0]-ibm[c])*s+ibb[c]; }
  const float *f1g=a.p[31],*f1b=a.p[32],*f1m=a.p[33],*f1v=a.p[34];
  for (int c=t;c<64;c+=256){ float s=f1g[c]/sqrtf(f1v[c]+EPSI); P[1312+c]=s; P[1376+c]=f1b[c]-f1m[c]*s; }
  const float *f2g=a.p[35],*f2b=a.p[36],*f2m=a.p[37],*f2v=a.p[38];
  for (int c=t;c<64;c+=256){ float s=f2g[c]/sqrtf(f2v[c]+EPSI); P[1440+c]=s; P[1504+c]=f2b[c]-f2m[c]*s; }
}

// ---------------- quantize + mode-pool(11,1,1) + fused 3->32->32 MLP ----------------
__global__ __launch_bounds__(256) void k_mode_mlp(const float* __restrict__ x,
                                                 const float* __restrict__ P,
                                                 float* __restrict__ dout) {
  __shared__ int qs[3*676];  // 3 channels, 26x26 levels
  int lx = threadIdx.x, ly = threadIdx.y;
  int tid = ly*16 + lx;
  int tx0 = blockIdx.x*16, ty0 = blockIdx.y*16;
  int b = blockIdx.z;
  for (int k = tid; k < 3*676; k += 256) {
    int cch = k/676; int rem = k - cch*676; int r = rem/26; int cc = rem - r*26;
    int gy = ty0 + r - 1, gx = tx0 + cc - 1;
    int q = 0;
    if ((unsigned)gy < 256u && (unsigned)gx < 256u) {
      float v = x[((size_t)(b*3+cch)*256 + gy)*256 + gx];
      q = (int)rintf(v*255.0f/16.0f);
      q = q < 0 ? 0 : (q > 16 ? 16 : q);
    }
    qs[k] = q;
  }
  __syncthreads();
  int oi = ty0 + ly, oj = tx0 + lx;
  if (oi >= 248 || oj >= 248) return;

  float md[3];
  #pragma unroll
  for (int cch = 0; cch < 3; cch++) {
    const int* qp = &qs[cch*676 + ly*26 + lx];
    unsigned h0=0,h1=0,h2=0,h3=0,h4=0;
    #pragma unroll 1
    for (int u = 0; u < 11; u++) {
      #pragma unroll
      for (int v = 0; v < 11; v++) {
        int q = qp[u*26 + v];
        unsigned inc = 1u << ((q & 3) << 3);
        int sel = q >> 2;
        h0 += (sel==0) ? inc : 0u;
        h1 += (sel==1) ? inc : 0u;
        h2 += (sel==2) ? inc : 0u;
        h3 += (sel==3) ? inc : 0u;
        h4 += (sel==4) ? inc : 0u;
      }
    }
    int best = -1, mode = 0;
    #define CHK(l, w) { int cnt = (int)((w >> (((l)&3)*8)) & 255u); if (cnt > best) { best = cnt; mode = (l); } }
    CHK(0,h0) CHK(1,h0) CHK(2,h0) CHK(3,h0)
    CHK(4,h1) CHK(5,h1) CHK(6,h1) CHK(7,h1)
    CHK(8,h2) CHK(9,h2) CHK(10,h2) CHK(11,h2)
    CHK(12,h3) CHK(13,h3) CHK(14,h3) CHK(15,h3)
    CHK(16,h4)
    #undef CHK
    md[cch] = (float)mode * 0.0625f;
  }

  const float* A1 = P;           const float* C1 = P + 96;
  const float* A2 = P + 128;     const float* C2 = P + 1152;
  float h[32];
  #pragma unroll
  for (int o = 0; o < 32; o++) {
    float v = C1[o] + A1[o*3]*md[0] + A1[o*3+1]*md[1] + A1[o*3+2]*md[2];
    h[o] = (v >= 0.f) ? v : 0.01f*v;
  }
  size_t ob = ((size_t)(b*32)*248 + oi)*248 + oj;
  #pragma unroll
  for (int o2 = 0; o2 < 32; o2++) {
    float acc = C2[o2];
    #pragma unroll
    for (int o = 0; o < 32; o++) acc += A2[o2*32+o]*h[o];
    acc = (acc >= 0.f) ? acc : 0.01f*acc;
    dout[ob + (size_t)o2*(248*248)] = acc;
  }
}

// ---------------- shared 3x3 conv, stride 3, pad 1 (248 -> 83) ----------------
__global__ void k_down(const float* __restrict__ in, float* __restrict__ out,
                       const float* __restrict__ scw, const float* __restrict__ scb) {
  const int Hin = 248, Hout = 83, total = 128*83*83;
  int idx = blockIdx.x*256 + threadIdx.x;
  if (idx >= total) return;
  float w[9];
  #pragma unroll
  for (int i = 0; i < 9; i++) w[i] = rfl(scw[i]);
  float bias = rfl(scb[0]);
  int j = idx % Hout; int t2 = idx / Hout; int i = t2 % Hout; int p = t2 / Hout;
  const float* base = in + (size_t)p*Hin*Hin;
  float s = bias;
  #pragma unroll
  for (int u = 0; u < 3; u++) {
    int r = 3*i - 1 + u;
    if ((unsigned)r < (unsigned)Hin) {
      #pragma unroll
      for (int v = 0; v < 3; v++) {
        int cc = 3*j - 1 + v;
        if ((unsigned)cc < (unsigned)Hin) s += base[(size_t)r*Hin + cc]*w[u*3+v];
      }
    }
  }
  out[idx] = s;
}

// ---------------- merged tail downsamples: 83->28->10->4->2, one block per (b,c) ----------------
__global__ __launch_bounds__(256) void k_down_rest(const float* __restrict__ in, float* __restrict__ ws,
                                                   const float* __restrict__ scw, const float* __restrict__ scb) {
  __shared__ float buf[6889 + 784 + 100 + 16];   // 31.2 KB
  int tid = threadIdx.x; int p = blockIdx.x;     // 128 blocks
  float w[9];
  #pragma unroll
  for (int i = 0; i < 9; i++) w[i] = rfl(scw[i]);
  float bias = rfl(scb[0]);
  const float* src = in + (size_t)p*6889;
  for (int k = tid; k < 6889; k += 256) buf[k] = src[k];
  __syncthreads();
  const int HIN[4] = {83,28,10,4}, HOUT[4] = {28,10,4,2};
  const int OIN[4] = {0, 6889, 6889+784, 6889+784+100};
  const size_t GOFF[4] = {P_D2, P_D3, P_D4, P_D5};
  #pragma unroll
  for (int st = 0; st < 4; st++) {
    const int hin = HIN[st], hout = HOUT[st];
    const float* bi = buf + OIN[st];
    float* bo = buf + OIN[st] + hin*hin;
    float* go = ws + GOFF[st] + (size_t)p*(hout*hout);
    for (int k = tid; k < hout*hout; k += 256) {
      int i = k/hout, j = k - i*hout;
      float s = bias;
      #pragma unroll
      for (int u = 0; u < 3; u++) {
        int r = 3*i - 1 + u;
        if ((unsigned)r < (unsigned)hin) {
          #pragma unroll
          for (int v = 0; v < 3; v++) {
            int cc = 3*j - 1 + v;
            if ((unsigned)cc < (unsigned)hin) s += bi[r*hin + cc]*w[u*3+v];
          }
        }
      }
      bo[k] = s; go[k] = s;
    }
    __syncthreads();
  }
}

// ---------------- pyramid: separable bilinear + dual 5x5 conv, 2x4 outputs/thread ----------------
// Block covers 64(w) x 32(h) outputs. hrow: x-lerped source rows, stride 96 (bank-aligned),
// rows {14,7,4,3,2} + 2 zero rows. Y-params computed ARITHMETICALLY per thread (no LDS
// indirection -> no serial b64->b128 chain). ONE barrier total.
__global__ __launch_bounds__(256, 4) void k_accum(const float* __restrict__ ws,
                                                  const float* __restrict__ iaw,
                                                  const float* __restrict__ ibw,
                                                  float* __restrict__ score) {
  __shared__ __align__(16) float hrow[3072];  // 32 rows x 96
  int tid = threadIdx.x;
  int c = blockIdx.y, b = blockIdx.z;
  int tx0 = (blockIdx.x & 3)*64, ty0 = (blockIdx.x >> 2)*32;
  int lx4 = (tid & 15)*4, ly = tid >> 4;      // 16x16 threads, 4w x 2h px each
  float sa = rfl(ws[1184+c]), Ca = rfl(ws[1216+c]), sb = rfl(ws[1248+c]), Cb = rfl(ws[1280+c]);
  float wa[25], wb[25];
  #pragma unroll
  for (int i = 0; i < 25; i++) { wa[i] = iaw[i]; wb[i] = ibw[i]; }

  const int NS[5]  = {83,28,10,4,2};
  const int HBF[5] = {0, 14*96, 21*96, 25*96, 28*96};
  const int ZROW = 30*96;
  const size_t OFF[5] = {P_D1,P_D2,P_D3,P_D4,P_D5};

  // ---- staging: x-lerped rows for all 5 levels + zero rows, ONE barrier ----
  for (int k = tid; k < 192; k += 256) hrow[ZROW + k] = 0.f;
  #pragma unroll
  for (int lvl = 0; lvl < 5; lvl++) {
    const int n = NS[lvl];
    const float inv = (float)n * (1.f/256.f);
    float f0 = ((float)(ty0-2)+0.5f)*inv - 0.5f;
    float f1 = ((float)(ty0+33)+0.5f)*inv - 0.5f;
    int yb0 = min(max((int)floorf(f0),0), n-2);
    int yb1 = min(max((int)floorf(f1),0), n-2);
    int rows = yb1 - yb0 + 2;
    const float* dp = ws + OFF[lvl] + (size_t)(b*32+c)*(n*n);
    for (int k = tid; k < rows*68; k += 256) {
      int r = k/68, zx = k - r*68;
      int gx = tx0 + zx - 2;
      float h = 0.f;
      if ((unsigned)gx < 256u) {
        float f = ((float)gx + 0.5f)*inv - 0.5f;
        float ff = floorf(f);
        int i0 = (int)ff;
        int xb = min(max(i0,0), n-2);
        float wx = (i0 < 0) ? 0.f : (i0 > n-2 ? 1.f : f - ff);
        const float* rp = dp + (yb0 + r)*n + xb;
        h = rp[0] + wx*(rp[1] - rp[0]);
      }
      hrow[HBF[lvl] + r*96 + zx] = h;
    }
  }
  __syncthreads();                             // the ONLY barrier

  // ---- compute ----
  float accA[8] = {0,0,0,0,0,0,0,0}, accB[8] = {0,0,0,0,0,0,0,0};
  int gy0 = ty0 + 2*ly - 2;
  #pragma unroll
  for (int lvl = 0; lvl < 5; lvl++) {
    const int n = NS[lvl];
    const float inv = (float)n * (1.f/256.f);
    float f0u = ((float)(ty0-2)+0.5f)*inv - 0.5f;
    int yb0 = min(max((int)floorf(f0u),0), n-2);           // uniform -> SGPR
    int obase = HBF[lvl] - yb0*96 + lx4;                   // uniform + lane part
    float cA0[4] = {0,0,0,0}, cA1[4] = {0,0,0,0};
    float cB0[4] = {0,0,0,0}, cB1[4] = {0,0,0,0};
    #pragma unroll
    for (int r = 0; r < 6; r++) {
      int gy = gy0 + r;
      float f = ((float)gy + 0.5f)*inv - 0.5f;
      float ff = floorf(f);
      int i0 = (int)ff;
      int yb = min(max(i0,0), n-2);
      float wy = (i0 < 0) ? 0.f : (i0 > n-2 ? 1.f : f - ff);
      bool valid = ((unsigned)gy < 256u);
      int off = valid ? (obase + yb*96) : (ZROW + lx4);
      wy = valid ? wy : 0.f;
      float4 a0 = *(const float4*)&hrow[off];
      float4 a1 = *(const float4*)&hrow[off+4];
      float4 b0 = *(const float4*)&hrow[off+96];
      float4 b1 = *(const float4*)&hrow[off+100];
      float z[8];
      z[0] = a0.x + wy*(b0.x - a0.x);
      z[1] = a0.y + wy*(b0.y - a0.y);
      z[2] = a0.z + wy*(b0.z - a0.z);
      z[3] = a0.w + wy*(b0.w - a0.w);
      z[4] = a1.x + wy*(b1.x - a1.x);
      z[5] = a1.y + wy*(b1.y - a1.y);
      z[6] = a1.z + wy*(b1.z - a1.z);
      z[7] = a1.w + wy*(b1.w - a1.w);
      if (r < 5) {                             // kernel row r for output row 0
        #pragma unroll
        for (int j = 0; j < 4; j++)
          #pragma unroll
          for (int v = 0; v < 5; v++) {
            cA0[j] += z[j+v]*wa[r*5+v];
            cB0[j] += z[j+v]*wb[r*5+v];
          }
      }
      if (r >= 1) {                            // kernel row r-1 for output row 1
        #pragma unroll
        for (int j = 0; j < 4; j++)
          #pragma unroll
          for (int v = 0; v < 5; v++) {
            cA1[j] += z[j+v]*wa[(r-1)*5+v];
            cB1[j] += z[j+v]*wb[(r-1)*5+v];
          }
      }
    }
    #pragma unroll
    for (int j = 0; j < 4; j++) {
      float a0v = cA0[j]*sa + Ca; accA[j]   += (a0v >= 0.f) ? a0v : 0.01f*a0v;
      float a1v = cA1[j]*sa + Ca; accA[4+j] += (a1v >= 0.f) ? a1v : 0.01f*a1v;
      float b0v = cB0[j]*sb + Cb; accB[j]   += (b0v >= 0.f) ? b0v : 0.01f*b0v;
      float b1v = cB1[j]*sb + Cb; accB[4+j] += (b1v >= 0.f) ? b1v : 0.01f*b1v;
    }
  }
  int oy = ty0 + 2*ly, ox = tx0 + lx4;
  size_t baseA = ((size_t)(b*64 + c)*256 + oy)*256 + ox;
  size_t baseB = ((size_t)(b*64 + 32 + c)*256 + oy)*256 + ox;
  *(float4*)&score[baseA]       = make_float4(accA[0],accA[1],accA[2],accA[3]);
  *(float4*)&score[baseA + 256] = make_float4(accA[4],accA[5],accA[6],accA[7]);
  *(float4*)&score[baseB]       = make_float4(accB[0],accB[1],accB[2],accB[3]);
  *(float4*)&score[baseB + 256] = make_float4(accB[4],accB[5],accB[6],accB[7]);
}

// ---------------- ft pass: BN -> MaxLeakyReLU -> BN -> EmphaseLocal ----------------
__global__ __launch_bounds__(256) void k_ft(const float* __restrict__ in,
                                            float* __restrict__ out,
                                            const float* __restrict__ P, float scale) {
  __shared__ float A[74*77];   // pointwise(y) with halo 5; stride 77 (conflict fix)
  __shared__ float Bf[64*77];  // vertical 11-sums
  int tid = threadIdx.x;
  int c = blockIdx.y, b = blockIdx.z;
  int ty0 = (blockIdx.x >> 2)*64, tx0 = (blockIdx.x & 3)*64;
  float fs1 = rfl(P[1312+c]), fc1 = rfl(P[1376+c]), fs2 = rfl(P[1440+c]), fc2 = rfl(P[1504+c]);
  const float* ip = in + (size_t)(b*64 + c)*65536;
  for (int k = tid; k < 1480; k += 256) {        // 74 rows x 20 aligned float4
    int ay = k/20, qx = k - ay*20;
    int gy = ty0 + ay - 5;
    int gx0 = tx0 - 8 + qx*4;
    float4 v = make_float4(0.f,0.f,0.f,0.f);
    bool rowok = ((unsigned)gy < 256u);
    if (rowok) {
      if (gx0 >= 0 && gx0 <= 252) v = *(const float4*)(ip + gy*256 + gx0);
      else {
        float* pv = (float*)&v;
        #pragma unroll
        for (int e = 0; e < 4; e++) { int gx = gx0+e; if ((unsigned)gx < 256u) pv[e] = ip[gy*256 + gx]; }
      }
    }
    float* pv = (float*)&v;
    int ax0 = gx0 - tx0 + 5;
    #pragma unroll
    for (int e = 0; e < 4; e++) {
      int ax = ax0 + e;
      if ((unsigned)ax < 74u) {
        int gx = gx0 + e;
        float y = 0.f;
        if (rowok && (unsigned)gx < 256u) {
          float t = pv[e]*fs1 + fc1;
          t = (t > 0.1f) ? t : 0.7f*t;
          y = t*fs2 + fc2;
        }
        A[ay*77 + ax] = y;
      }
    }
  }
  __syncthreads();
  for (int task = tid; task < 296; task += 256) {   // 74 cols x 4 chunks of 16 rows
    int chunk = task/74; int col = task - chunk*74;
    int r0 = chunk*16;
    float s = 0.f;
    #pragma unroll
    for (int u = 0; u < 11; u++) s += A[(r0+u)*77 + col];
    Bf[r0*77 + col] = s;
    #pragma unroll
    for (int r = 1; r < 16; r++) {
      s += A[(r0+r+10)*77 + col] - A[(r0+r-1)*77 + col];
      Bf[(r0+r)*77 + col] = s;
    }
  }
  __syncthreads();
  {
    int r = tid >> 2; int c0 = (tid & 3)*16;        // 64 rows x 4 chunks of 16 cols
    float s = 0.f;
    #pragma unroll
    for (int v = 0; v < 11; v++) s += Bf[r*77 + c0 + v];
    float* op = out + (size_t)(b*64 + c)*65536 + (size_t)(ty0+r)*256 + tx0;
    float4 bufv;
    #pragma unroll
    for (int j = 0; j < 16; j++) {
      float mean = s*(1.f/121.f);
      float y = A[(r+5)*77 + c0 + j + 5];
      float sig = 1.f/(1.f + __expf(-(y - mean)));
      ((float*)&bufv)[j & 3] = y*sig*scale;
      if ((j & 3) == 3) *(float4*)(op + c0 + (j & ~3)) = bufv;
      if (j < 15) s += Bf[r*77 + c0 + j + 11] - Bf[r*77 + c0 + j];
    }
  }
}

// ---------------- launch ----------------
extern "C" void kernel_launch(void* const* d_in, const int* in_sizes, int n_in,
                              void* d_out, int out_size, void* d_ws, size_t ws_size,
                              hipStream_t stream) {
  const float* x = (const float*)d_in[0];
  float* ws = (float*)d_ws;
  float* out = (float*)d_out;

  PrepArgs pa;
  for (int i = 0; i < 39; i++) pa.p[i] = (const float*)d_in[i];
  k_prep<<<dim3(1), dim3(256), 0, stream>>>(pa, ws);

  k_mode_mlp<<<dim3(16,16,4), dim3(16,16), 0, stream>>>(x, ws, ws + P_D);

  const float* scw = (const float*)d_in[17];
  const float* scb = (const float*)d_in[18];
  {
    int total = 128*83*83;
    k_down<<<dim3((total+255)/256), dim3(256), 0, stream>>>(ws + P_D, ws + P_D1, scw, scb);
  }
  k_down_rest<<<dim3(128), dim3(256), 0, stream>>>(ws + P_D1, ws, scw, scb);

  k_accum<<<dim3(32,32,4), dim3(256), 0, stream>>>(ws, (const float*)d_in[19],
                                                   (const float*)d_in[25], ws + P_SCORE);

  // ft x3, ping-pong ws_score <-> d_out; /5 folded into last pass
  k_ft<<<dim3(16,64,4), dim3(256), 0, stream>>>(ws + P_SCORE, out, ws, 1.f);
  k_ft<<<dim3(16,64,4), dim3(256), 0, stream>>>(out, ws + P_SCORE, ws, 1.f);
  k_ft<<<dim3(16,64,4), dim3(256), 0, stream>>>(ws + P_SCORE, out, ws, 0.2f);
}

// Round 6
// 714.909 us; speedup vs baseline: 3.0774x; 3.0774x over previous
//
#include <hip/hip_runtime.h>
#include <math.h>

#define EPSI 1e-5f

// ---------------- workspace layout (floats) ----------------
//   A1[96] @0, C1[32] @96, A2[1024] @128, C2[32] @1152,
//   sa[32] @1184, Ca[32] @1216, sb[32] @1248, Cb[32] @1280,
//   fs1[64] @1312, fc1[64] @1376, fs2[64] @1440, fc2[64] @1504
#define P_D1 2048                    // 128*83*83 = 881792
#define P_D2 (P_D1 + 128*83*83)
#define P_D3 (P_D2 + 128*28*28)
#define P_D4 (P_D3 + 128*10*10)
#define P_D5 (P_D4 + 128*4*4)
#define P_SCORE (P_D5 + 128*2*2)     // 4*64*256*256 = 16777216 floats
#define P_D  P_SCORE                 // d (4,32,248,248) aliases score head (dead before accum)

__device__ __forceinline__ float rfl(float x) {
  return __builtin_bit_cast(float, __builtin_amdgcn_readfirstlane(__builtin_bit_cast(int, x)));
}

struct PrepArgs { const float* p[39]; };

// ---------------- prep: fold all affine params ----------------
__global__ void k_prep(PrepArgs a, float* __restrict__ P) {
  int t = threadIdx.x;
  const float *w1=a.p[1],*b1=a.p[2],*w2=a.p[3],*b2=a.p[4],*g1=a.p[5],*bb1=a.p[6],*m1=a.p[7],*v1=a.p[8];
  const float *w3=a.p[9],*b3=a.p[10],*w4=a.p[11],*b4=a.p[12],*g2=a.p[13],*bb2=a.p[14],*m2=a.p[15],*v2=a.p[16];
  for (int i=t;i<96;i+=256){ int o=i/3; float s=g1[o]/sqrtf(v1[o]+EPSI); P[i]=w1[i]*w2[o]*s; }
  for (int o=t;o<32;o+=256){ float s=g1[o]/sqrtf(v1[o]+EPSI); P[96+o]=(b1[o]*w2[o]+b2[o]-m1[o])*s+bb1[o]; }
  for (int i=t;i<1024;i+=256){ int o2=i/32; float s=g2[o2]/sqrtf(v2[o2]+EPSI); P[128+i]=w3[i]*w4[o2]*s; }
  for (int o=t;o<32;o+=256){ float s=g2[o]/sqrtf(v2[o]+EPSI); P[1152+o]=(b3[o]*w4[o]+b4[o]-m2[o])*s+bb2[o]; }
  const float *iag=a.p[21],*iab=a.p[22],*iam=a.p[23],*iav=a.p[24],*iabias=a.p[20];
  for (int c=t;c<32;c+=256){ float s=iag[c]/sqrtf(iav[c]+EPSI); P[1184+c]=s; P[1216+c]=(iabias[0]-iam[c])*s+iab[c]; }
  const float *ibg=a.p[27],*ibb=a.p[28],*ibm=a.p[29],*ibv=a.p[30],*ibbias=a.p[26];
  for (int c=t;c<32;c+=256){ float s=ibg[c]/sqrtf(ibv[c]+EPSI); P[1248+c]=s; P[1280+c]=(ibbias[0]-ibm[c])*s+ibb[c]; }
  const float *f1g=a.p[31],*f1b=a.p[32],*f1m=a.p[33],*f1v=a.p[34];
  for (int c=t;c<64;c+=256){ float s=f1g[c]/sqrtf(f1v[c]+EPSI); P[1312+c]=s; P[1376+c]=f1b[c]-f1m[c]*s; }
  const float *f2g=a.p[35],*f2b=a.p[36],*f2m=a.p[37],*f2v=a.p[38];
  for (int c=t;c<64;c+=256){ float s=f2g[c]/sqrtf(f2v[c]+EPSI); P[1440+c]=s; P[1504+c]=f2b[c]-f2m[c]*s; }
}

// ---------------- quantize + mode-pool(11,1,1) + fused 3->32->32 MLP ----------------
__global__ __launch_bounds__(256) void k_mode_mlp(const float* __restrict__ x,
                                                 const float* __restrict__ P,
                                                 float* __restrict__ dout) {
  __shared__ int qs[3*676];  // 3 channels, 26x26 levels
  int lx = threadIdx.x, ly = threadIdx.y;
  int tid = ly*16 + lx;
  int tx0 = blockIdx.x*16, ty0 = blockIdx.y*16;
  int b = blockIdx.z;
  for (int k = tid; k < 3*676; k += 256) {
    int cch = k/676; int rem = k - cch*676; int r = rem/26; int cc = rem - r*26;
    int gy = ty0 + r - 1, gx = tx0 + cc - 1;
    int q = 0;
    if ((unsigned)gy < 256u && (unsigned)gx < 256u) {
      float v = x[((size_t)(b*3+cch)*256 + gy)*256 + gx];
      q = (int)rintf(v*255.0f/16.0f);
      q = q < 0 ? 0 : (q > 16 ? 16 : q);
    }
    qs[k] = q;
  }
  __syncthreads();
  int oi = ty0 + ly, oj = tx0 + lx;
  if (oi >= 248 || oj >= 248) return;

  float md[3];
  #pragma unroll
  for (int cch = 0; cch < 3; cch++) {
    const int* qp = &qs[cch*676 + ly*26 + lx];
    unsigned h0=0,h1=0,h2=0,h3=0,h4=0;
    #pragma unroll 1
    for (int u = 0; u < 11; u++) {
      #pragma unroll
      for (int v = 0; v < 11; v++) {
        int q = qp[u*26 + v];
        unsigned inc = 1u << ((q & 3) << 3);
        int sel = q >> 2;
        h0 += (sel==0) ? inc : 0u;
        h1 += (sel==1) ? inc : 0u;
        h2 += (sel==2) ? inc : 0u;
        h3 += (sel==3) ? inc : 0u;
        h4 += (sel==4) ? inc : 0u;
      }
    }
    int best = -1, mode = 0;
    #define CHK(l, w) { int cnt = (int)((w >> (((l)&3)*8)) & 255u); if (cnt > best) { best = cnt; mode = (l); } }
    CHK(0,h0) CHK(1,h0) CHK(2,h0) CHK(3,h0)
    CHK(4,h1) CHK(5,h1) CHK(6,h1) CHK(7,h1)
    CHK(8,h2) CHK(9,h2) CHK(10,h2) CHK(11,h2)
    CHK(12,h3) CHK(13,h3) CHK(14,h3) CHK(15,h3)
    CHK(16,h4)
    #undef CHK
    md[cch] = (float)mode * 0.0625f;
  }

  const float* A1 = P;           const float* C1 = P + 96;
  const float* A2 = P + 128;     const float* C2 = P + 1152;
  float h[32];
  #pragma unroll
  for (int o = 0; o < 32; o++) {
    float v = C1[o] + A1[o*3]*md[0] + A1[o*3+1]*md[1] + A1[o*3+2]*md[2];
    h[o] = (v >= 0.f) ? v : 0.01f*v;
  }
  size_t ob = ((size_t)(b*32)*248 + oi)*248 + oj;
  #pragma unroll
  for (int o2 = 0; o2 < 32; o2++) {
    float acc = C2[o2];
    #pragma unroll
    for (int o = 0; o < 32; o++) acc += A2[o2*32+o]*h[o];
    acc = (acc >= 0.f) ? acc : 0.01f*acc;
    dout[ob + (size_t)o2*(248*248)] = acc;
  }
}

// ---------------- shared 3x3 conv, stride 3, pad 1 (248 -> 83) ----------------
__global__ void k_down(const float* __restrict__ in, float* __restrict__ out,
                       const float* __restrict__ scw, const float* __restrict__ scb) {
  const int Hin = 248, Hout = 83, total = 128*83*83;
  int idx = blockIdx.x*256 + threadIdx.x;
  if (idx >= total) return;
  float w[9];
  #pragma unroll
  for (int i = 0; i < 9; i++) w[i] = rfl(scw[i]);
  float bias = rfl(scb[0]);
  int j = idx % Hout; int t2 = idx / Hout; int i = t2 % Hout; int p = t2 / Hout;
  const float* base = in + (size_t)p*Hin*Hin;
  float s = bias;
  #pragma unroll
  for (int u = 0; u < 3; u++) {
    int r = 3*i - 1 + u;
    if ((unsigned)r < (unsigned)Hin) {
      #pragma unroll
      for (int v = 0; v < 3; v++) {
        int cc = 3*j - 1 + v;
        if ((unsigned)cc < (unsigned)Hin) s += base[(size_t)r*Hin + cc]*w[u*3+v];
      }
    }
  }
  out[idx] = s;
}

// ---------------- merged tail downsamples: 83->28->10->4->2, one block per (b,c) ----------------
__global__ __launch_bounds__(256) void k_down_rest(const float* __restrict__ in, float* __restrict__ ws,
                                                   const float* __restrict__ scw, const float* __restrict__ scb) {
  __shared__ float buf[6889 + 784 + 100 + 16];   // 31.2 KB
  int tid = threadIdx.x; int p = blockIdx.x;     // 128 blocks
  float w[9];
  #pragma unroll
  for (int i = 0; i < 9; i++) w[i] = rfl(scw[i]);
  float bias = rfl(scb[0]);
  const float* src = in + (size_t)p*6889;
  for (int k = tid; k < 6889; k += 256) buf[k] = src[k];
  __syncthreads();
  const int HIN[4] = {83,28,10,4}, HOUT[4] = {28,10,4,2};
  const int OIN[4] = {0, 6889, 6889+784, 6889+784+100};
  const size_t GOFF[4] = {P_D2, P_D3, P_D4, P_D5};
  #pragma unroll
  for (int st = 0; st < 4; st++) {
    const int hin = HIN[st], hout = HOUT[st];
    const float* bi = buf + OIN[st];
    float* bo = buf + OIN[st] + hin*hin;
    float* go = ws + GOFF[st] + (size_t)p*(hout*hout);
    for (int k = tid; k < hout*hout; k += 256) {
      int i = k/hout, j = k - i*hout;
      float s = bias;
      #pragma unroll
      for (int u = 0; u < 3; u++) {
        int r = 3*i - 1 + u;
        if ((unsigned)r < (unsigned)hin) {
          #pragma unroll
          for (int v = 0; v < 3; v++) {
            int cc = 3*j - 1 + v;
            if ((unsigned)cc < (unsigned)hin) s += bi[r*hin + cc]*w[u*3+v];
          }
        }
      }
      bo[k] = s; go[k] = s;
    }
    __syncthreads();
  }
}

// ---------------- pyramid: separable bilinear + dual 5x5 conv, 2x4 outputs/thread ----------------
// Block covers 64(w) x 32(h) outputs. hrow: x-lerped source rows, stride 96 (bank-aligned),
// rows {14,7,4,3,2} + 2 zero rows. Y-params computed arithmetically per thread.
// Conv weights forced into SGPRs via readfirstlane (v_fma takes 1 SGPR operand) —
// this is the legit way to cut ~50 VGPRs (R5's launch_bounds force spilled to scratch).
__global__ __launch_bounds__(256) void k_accum(const float* __restrict__ ws,
                                               const float* __restrict__ iaw,
                                               const float* __restrict__ ibw,
                                               float* __restrict__ score) {
  __shared__ __align__(16) float hrow[3072];  // 32 rows x 96
  int tid = threadIdx.x;
  int c = blockIdx.y, b = blockIdx.z;
  int tx0 = (blockIdx.x & 3)*64, ty0 = (blockIdx.x >> 2)*32;
  int lx4 = (tid & 15)*4, ly = tid >> 4;      // 16x16 threads, 4w x 2h px each
  float sa = rfl(ws[1184+c]), Ca = rfl(ws[1216+c]), sb = rfl(ws[1248+c]), Cb = rfl(ws[1280+c]);
  float wa[25], wb[25];                        // SGPR-resident (rfl), not VGPR
  #pragma unroll
  for (int i = 0; i < 25; i++) { wa[i] = rfl(iaw[i]); wb[i] = rfl(ibw[i]); }

  const int NS[5]  = {83,28,10,4,2};
  const int HBF[5] = {0, 14*96, 21*96, 25*96, 28*96};
  const int ZROW = 30*96;
  const size_t OFF[5] = {P_D1,P_D2,P_D3,P_D4,P_D5};

  // ---- staging: x-lerped rows for all 5 levels + zero rows, ONE barrier ----
  for (int k = tid; k < 192; k += 256) hrow[ZROW + k] = 0.f;
  #pragma unroll
  for (int lvl = 0; lvl < 5; lvl++) {
    const int n = NS[lvl];
    const float inv = (float)n * (1.f/256.f);
    float f0 = ((float)(ty0-2)+0.5f)*inv - 0.5f;
    float f1 = ((float)(ty0+33)+0.5f)*inv - 0.5f;
    int yb0 = min(max((int)floorf(f0),0), n-2);
    int yb1 = min(max((int)floorf(f1),0), n-2);
    int rows = yb1 - yb0 + 2;
    const float* dp = ws + OFF[lvl] + (size_t)(b*32+c)*(n*n);
    for (int k = tid; k < rows*68; k += 256) {
      int r = k/68, zx = k - r*68;
      int gx = tx0 + zx - 2;
      float h = 0.f;
      if ((unsigned)gx < 256u) {
        float f = ((float)gx + 0.5f)*inv - 0.5f;
        float ff = floorf(f);
        int i0 = (int)ff;
        int xb = min(max(i0,0), n-2);
        float wx = (i0 < 0) ? 0.f : (i0 > n-2 ? 1.f : f - ff);
        const float* rp = dp + (yb0 + r)*n + xb;
        h = rp[0] + wx*(rp[1] - rp[0]);
      }
      hrow[HBF[lvl] + r*96 + zx] = h;
    }
  }
  __syncthreads();                             // the ONLY barrier

  // ---- compute ----
  float accA[8] = {0,0,0,0,0,0,0,0}, accB[8] = {0,0,0,0,0,0,0,0};
  int gy0 = ty0 + 2*ly - 2;
  #pragma unroll
  for (int lvl = 0; lvl < 5; lvl++) {
    const int n = NS[lvl];
    const float inv = (float)n * (1.f/256.f);
    float f0u = ((float)(ty0-2)+0.5f)*inv - 0.5f;
    int yb0 = min(max((int)floorf(f0u),0), n-2);           // uniform -> SGPR
    int obase = HBF[lvl] - yb0*96 + lx4;                   // uniform + lane part
    float cA0[4] = {0,0,0,0}, cA1[4] = {0,0,0,0};
    float cB0[4] = {0,0,0,0}, cB1[4] = {0,0,0,0};
    #pragma unroll
    for (int r = 0; r < 6; r++) {
      int gy = gy0 + r;
      float f = ((float)gy + 0.5f)*inv - 0.5f;
      float ff = floorf(f);
      int i0 = (int)ff;
      int yb = min(max(i0,0), n-2);
      float wy = (i0 < 0) ? 0.f : (i0 > n-2 ? 1.f : f - ff);
      bool valid = ((unsigned)gy < 256u);
      int off = valid ? (obase + yb*96) : (ZROW + lx4);
      wy = valid ? wy : 0.f;
      float4 a0 = *(const float4*)&hrow[off];
      float4 a1 = *(const float4*)&hrow[off+4];
      float4 b0 = *(const float4*)&hrow[off+96];
      float4 b1 = *(const float4*)&hrow[off+100];
      float z[8];
      z[0] = a0.x + wy*(b0.x - a0.x);
      z[1] = a0.y + wy*(b0.y - a0.y);
      z[2] = a0.z + wy*(b0.z - a0.z);
      z[3] = a0.w + wy*(b0.w - a0.w);
      z[4] = a1.x + wy*(b1.x - a1.x);
      z[5] = a1.y + wy*(b1.y - a1.y);
      z[6] = a1.z + wy*(b1.z - a1.z);
      z[7] = a1.w + wy*(b1.w - a1.w);
      if (r < 5) {                             // kernel row r for output row 0
        #pragma unroll
        for (int j = 0; j < 4; j++)
          #pragma unroll
          for (int v = 0; v < 5; v++) {
            cA0[j] += z[j+v]*wa[r*5+v];
            cB0[j] += z[j+v]*wb[r*5+v];
          }
      }
      if (r >= 1) {                            // kernel row r-1 for output row 1
        #pragma unroll
        for (int j = 0; j < 4; j++)
          #pragma unroll
          for (int v = 0; v < 5; v++) {
            cA1[j] += z[j+v]*wa[(r-1)*5+v];
            cB1[j] += z[j+v]*wb[(r-1)*5+v];
          }
      }
    }
    #pragma unroll
    for (int j = 0; j < 4; j++) {
      float a0v = cA0[j]*sa + Ca; accA[j]   += (a0v >= 0.f) ? a0v : 0.01f*a0v;
      float a1v = cA1[j]*sa + Ca; accA[4+j] += (a1v >= 0.f) ? a1v : 0.01f*a1v;
      float b0v = cB0[j]*sb + Cb; accB[j]   += (b0v >= 0.f) ? b0v : 0.01f*b0v;
      float b1v = cB1[j]*sb + Cb; accB[4+j] += (b1v >= 0.f) ? b1v : 0.01f*b1v;
    }
  }
  int oy = ty0 + 2*ly, ox = tx0 + lx4;
  size_t baseA = ((size_t)(b*64 + c)*256 + oy)*256 + ox;
  size_t baseB = ((size_t)(b*64 + 32 + c)*256 + oy)*256 + ox;
  *(float4*)&score[baseA]       = make_float4(accA[0],accA[1],accA[2],accA[3]);
  *(float4*)&score[baseA + 256] = make_float4(accA[4],accA[5],accA[6],accA[7]);
  *(float4*)&score[baseB]       = make_float4(accB[0],accB[1],accB[2],accB[3]);
  *(float4*)&score[baseB + 256] = make_float4(accB[4],accB[5],accB[6],accB[7]);
}

// ---------------- ft pass: BN -> MaxLeakyReLU -> BN -> EmphaseLocal ----------------
__global__ __launch_bounds__(256) void k_ft(const float* __restrict__ in,
                                            float* __restrict__ out,
                                            const float* __restrict__ P, float scale) {
  __shared__ float A[74*77];   // pointwise(y) with halo 5; stride 77 (conflict fix)
  __shared__ float Bf[64*77];  // vertical 11-sums
  int tid = threadIdx.x;
  int c = blockIdx.y, b = blockIdx.z;
  int ty0 = (blockIdx.x >> 2)*64, tx0 = (blockIdx.x & 3)*64;
  float fs1 = rfl(P[1312+c]), fc1 = rfl(P[1376+c]), fs2 = rfl(P[1440+c]), fc2 = rfl(P[1504+c]);
  const float* ip = in + (size_t)(b*64 + c)*65536;
  for (int k = tid; k < 1480; k += 256) {        // 74 rows x 20 aligned float4
    int ay = k/20, qx = k - ay*20;
    int gy = ty0 + ay - 5;
    int gx0 = tx0 - 8 + qx*4;
    float4 v = make_float4(0.f,0.f,0.f,0.f);
    bool rowok = ((unsigned)gy < 256u);
    if (rowok) {
      if (gx0 >= 0 && gx0 <= 252) v = *(const float4*)(ip + gy*256 + gx0);
      else {
        float* pv = (float*)&v;
        #pragma unroll
        for (int e = 0; e < 4; e++) { int gx = gx0+e; if ((unsigned)gx < 256u) pv[e] = ip[gy*256 + gx]; }
      }
    }
    float* pv = (float*)&v;
    int ax0 = gx0 - tx0 + 5;
    #pragma unroll
    for (int e = 0; e < 4; e++) {
      int ax = ax0 + e;
      if ((unsigned)ax < 74u) {
        int gx = gx0 + e;
        float y = 0.f;
        if (rowok && (unsigned)gx < 256u) {
          float t = pv[e]*fs1 + fc1;
          t = (t > 0.1f) ? t : 0.7f*t;
          y = t*fs2 + fc2;
        }
        A[ay*77 + ax] = y;
      }
    }
  }
  __syncthreads();
  for (int task = tid; task < 296; task += 256) {   // 74 cols x 4 chunks of 16 rows
    int chunk = task/74; int col = task - chunk*74;
    int r0 = chunk*16;
    float s = 0.f;
    #pragma unroll
    for (int u = 0; u < 11; u++) s += A[(r0+u)*77 + col];
    Bf[r0*77 + col] = s;
    #pragma unroll
    for (int r = 1; r < 16; r++) {
      s += A[(r0+r+10)*77 + col] - A[(r0+r-1)*77 + col];
      Bf[(r0+r)*77 + col] = s;
    }
  }
  __syncthreads();
  {
    int r = tid >> 2; int c0 = (tid & 3)*16;        // 64 rows x 4 chunks of 16 cols
    float s = 0.f;
    #pragma unroll
    for (int v = 0; v < 11; v++) s += Bf[r*77 + c0 + v];
    float* op = out + (size_t)(b*64 + c)*65536 + (size_t)(ty0+r)*256 + tx0;
    float4 bufv;
    #pragma unroll
    for (int j = 0; j < 16; j++) {
      float mean = s*(1.f/121.f);
      float y = A[(r+5)*77 + c0 + j + 5];
      float sig = 1.f/(1.f + __expf(-(y - mean)));
      ((float*)&bufv)[j & 3] = y*sig*scale;
      if ((j & 3) == 3) *(float4*)(op + c0 + (j & ~3)) = bufv;
      if (j < 15) s += Bf[r*77 + c0 + j + 11] - Bf[r*77 + c0 + j];
    }
  }
}

// ---------------- launch ----------------
extern "C" void kernel_launch(void* const* d_in, const int* in_sizes, int n_in,
                              void* d_out, int out_size, void* d_ws, size_t ws_size,
                              hipStream_t stream) {
  const float* x = (const float*)d_in[0];
  float* ws = (float*)d_ws;
  float* out = (float*)d_out;

  PrepArgs pa;
  for (int i = 0; i < 39; i++) pa.p[i] = (const float*)d_in[i];
  k_prep<<<dim3(1), dim3(256), 0, stream>>>(pa, ws);

  k_mode_mlp<<<dim3(16,16,4), dim3(16,16), 0, stream>>>(x, ws, ws + P_D);

  const float* scw = (const float*)d_in[17];
  const float* scb = (const float*)d_in[18];
  {
    int total = 128*83*83;
    k_down<<<dim3((total+255)/256), dim3(256), 0, stream>>>(ws + P_D, ws + P_D1, scw, scb);
  }
  k_down_rest<<<dim3(128), dim3(256), 0, stream>>>(ws + P_D1, ws, scw, scb);

  k_accum<<<dim3(32,32,4), dim3(256), 0, stream>>>(ws, (const float*)d_in[19],
                                                   (const float*)d_in[25], ws + P_SCORE);

  // ft x3, ping-pong ws_score <-> d_out; /5 folded into last pass
  k_ft<<<dim3(16,64,4), dim3(256), 0, stream>>>(ws + P_SCORE, out, ws, 1.f);
  k_ft<<<dim3(16,64,4), dim3(256), 0, stream>>>(out, ws + P_SCORE, ws, 1.f);
  k_ft<<<dim3(16,64,4), dim3(256), 0, stream>>>(ws + P_SCORE, out, ws, 0.2f);
}

// Round 7
// 608.141 us; speedup vs baseline: 3.6177x; 1.1756x over previous
//
#include <hip/hip_runtime.h>
#include <math.h>

#define EPSI 1e-5f

// ---------------- workspace layout (floats) ----------------
//   A1[96] @0, C1[32] @96, A2[1024] @128, C2[32] @1152,
//   sa[32] @1184, Ca[32] @1216, sb[32] @1248, Cb[32] @1280,
//   fs1[64] @1312, fc1[64] @1376, fs2[64] @1440, fc2[64] @1504
#define P_D1 2048                    // 128*83*83 = 881792
#define P_D2 (P_D1 + 128*83*83)
#define P_D3 (P_D2 + 128*28*28)
#define P_D4 (P_D3 + 128*10*10)
#define P_D5 (P_D4 + 128*4*4)
#define P_SCORE (P_D5 + 128*2*2)     // 4*64*256*256 = 16777216 floats
#define P_D  P_SCORE                 // d (4,32,248,248) aliases score head (dead before accum)

__device__ __forceinline__ float rfl(float x) {
  return __builtin_bit_cast(float, __builtin_amdgcn_readfirstlane(__builtin_bit_cast(int, x)));
}

struct PrepArgs { const float* p[39]; };

// ---------------- prep: fold all affine params ----------------
__global__ void k_prep(PrepArgs a, float* __restrict__ P) {
  int t = threadIdx.x;
  const float *w1=a.p[1],*b1=a.p[2],*w2=a.p[3],*b2=a.p[4],*g1=a.p[5],*bb1=a.p[6],*m1=a.p[7],*v1=a.p[8];
  const float *w3=a.p[9],*b3=a.p[10],*w4=a.p[11],*b4=a.p[12],*g2=a.p[13],*bb2=a.p[14],*m2=a.p[15],*v2=a.p[16];
  for (int i=t;i<96;i+=256){ int o=i/3; float s=g1[o]/sqrtf(v1[o]+EPSI); P[i]=w1[i]*w2[o]*s; }
  for (int o=t;o<32;o+=256){ float s=g1[o]/sqrtf(v1[o]+EPSI); P[96+o]=(b1[o]*w2[o]+b2[o]-m1[o])*s+bb1[o]; }
  for (int i=t;i<1024;i+=256){ int o2=i/32; float s=g2[o2]/sqrtf(v2[o2]+EPSI); P[128+i]=w3[i]*w4[o2]*s; }
  for (int o=t;o<32;o+=256){ float s=g2[o]/sqrtf(v2[o]+EPSI); P[1152+o]=(b3[o]*w4[o]+b4[o]-m2[o])*s+bb2[o]; }
  const float *iag=a.p[21],*iab=a.p[22],*iam=a.p[23],*iav=a.p[24],*iabias=a.p[20];
  for (int c=t;c<32;c+=256){ float s=iag[c]/sqrtf(iav[c]+EPSI); P[1184+c]=s; P[1216+c]=(iabias[0]-iam[c])*s+iab[c]; }
  const float *ibg=a.p[27],*ibb=a.p[28],*ibm=a.p[29],*ibv=a.p[30],*ibbias=a.p[26];
  for (int c=t;c<32;c+=256){ float s=ibg[c]/sqrtf(ibv[c]+EPSI); P[1248+c]=s; P[1280+c]=(ibbias[0]-ibm[c])*s+ibb[c]; }
  const float *f1g=a.p[31],*f1b=a.p[32],*f1m=a.p[33],*f1v=a.p[34];
  for (int c=t;c<64;c+=256){ float s=f1g[c]/sqrtf(f1v[c]+EPSI); P[1312+c]=s; P[1376+c]=f1b[c]-f1m[c]*s; }
  const float *f2g=a.p[35],*f2b=a.p[36],*f2m=a.p[37],*f2v=a.p[38];
  for (int c=t;c<64;c+=256){ float s=f2g[c]/sqrtf(f2v[c]+EPSI); P[1440+c]=s; P[1504+c]=f2b[c]-f2m[c]*s; }
}

// ---------------- quantize + mode-pool(11,1,1) + fused 3->32->32 MLP ----------------
__global__ __launch_bounds__(256) void k_mode_mlp(const float* __restrict__ x,
                                                 const float* __restrict__ P,
                                                 float* __restrict__ dout) {
  __shared__ int qs[3*676];  // 3 channels, 26x26 levels
  int lx = threadIdx.x, ly = threadIdx.y;
  int tid = ly*16 + lx;
  int tx0 = blockIdx.x*16, ty0 = blockIdx.y*16;
  int b = blockIdx.z;
  for (int k = tid; k < 3*676; k += 256) {
    int cch = k/676; int rem = k - cch*676; int r = rem/26; int cc = rem - r*26;
    int gy = ty0 + r - 1, gx = tx0 + cc - 1;
    int q = 0;
    if ((unsigned)gy < 256u && (unsigned)gx < 256u) {
      float v = x[((size_t)(b*3+cch)*256 + gy)*256 + gx];
      q = (int)rintf(v*255.0f/16.0f);
      q = q < 0 ? 0 : (q > 16 ? 16 : q);
    }
    qs[k] = q;
  }
  __syncthreads();
  int oi = ty0 + ly, oj = tx0 + lx;
  if (oi >= 248 || oj >= 248) return;

  float md[3];
  #pragma unroll
  for (int cch = 0; cch < 3; cch++) {
    const int* qp = &qs[cch*676 + ly*26 + lx];
    unsigned h0=0,h1=0,h2=0,h3=0,h4=0;
    #pragma unroll 1
    for (int u = 0; u < 11; u++) {
      #pragma unroll
      for (int v = 0; v < 11; v++) {
        int q = qp[u*26 + v];
        unsigned inc = 1u << ((q & 3) << 3);
        int sel = q >> 2;
        h0 += (sel==0) ? inc : 0u;
        h1 += (sel==1) ? inc : 0u;
        h2 += (sel==2) ? inc : 0u;
        h3 += (sel==3) ? inc : 0u;
        h4 += (sel==4) ? inc : 0u;
      }
    }
    int best = -1, mode = 0;
    #define CHK(l, w) { int cnt = (int)((w >> (((l)&3)*8)) & 255u); if (cnt > best) { best = cnt; mode = (l); } }
    CHK(0,h0) CHK(1,h0) CHK(2,h0) CHK(3,h0)
    CHK(4,h1) CHK(5,h1) CHK(6,h1) CHK(7,h1)
    CHK(8,h2) CHK(9,h2) CHK(10,h2) CHK(11,h2)
    CHK(12,h3) CHK(13,h3) CHK(14,h3) CHK(15,h3)
    CHK(16,h4)
    #undef CHK
    md[cch] = (float)mode * 0.0625f;
  }

  const float* A1 = P;           const float* C1 = P + 96;
  const float* A2 = P + 128;     const float* C2 = P + 1152;
  float h[32];
  #pragma unroll
  for (int o = 0; o < 32; o++) {
    float v = C1[o] + A1[o*3]*md[0] + A1[o*3+1]*md[1] + A1[o*3+2]*md[2];
    h[o] = (v >= 0.f) ? v : 0.01f*v;
  }
  size_t ob = ((size_t)(b*32)*248 + oi)*248 + oj;
  #pragma unroll
  for (int o2 = 0; o2 < 32; o2++) {
    float acc = C2[o2];
    #pragma unroll
    for (int o = 0; o < 32; o++) acc += A2[o2*32+o]*h[o];
    acc = (acc >= 0.f) ? acc : 0.01f*acc;
    dout[ob + (size_t)o2*(248*248)] = acc;
  }
}

// ---------------- shared 3x3 conv, stride 3, pad 1 (248 -> 83) ----------------
__global__ void k_down(const float* __restrict__ in, float* __restrict__ out,
                       const float* __restrict__ scw, const float* __restrict__ scb) {
  const int Hin = 248, Hout = 83, total = 128*83*83;
  int idx = blockIdx.x*256 + threadIdx.x;
  if (idx >= total) return;
  float w[9];
  #pragma unroll
  for (int i = 0; i < 9; i++) w[i] = rfl(scw[i]);
  float bias = rfl(scb[0]);
  int j = idx % Hout; int t2 = idx / Hout; int i = t2 % Hout; int p = t2 / Hout;
  const float* base = in + (size_t)p*Hin*Hin;
  float s = bias;
  #pragma unroll
  for (int u = 0; u < 3; u++) {
    int r = 3*i - 1 + u;
    if ((unsigned)r < (unsigned)Hin) {
      #pragma unroll
      for (int v = 0; v < 3; v++) {
        int cc = 3*j - 1 + v;
        if ((unsigned)cc < (unsigned)Hin) s += base[(size_t)r*Hin + cc]*w[u*3+v];
      }
    }
  }
  out[idx] = s;
}

// ---------------- merged tail downsamples: 83->28->10->4->2, one block per (b,c) ----------------
__global__ __launch_bounds__(256) void k_down_rest(const float* __restrict__ in, float* __restrict__ ws,
                                                   const float* __restrict__ scw, const float* __restrict__ scb) {
  __shared__ float buf[6889 + 784 + 100 + 16];   // 31.2 KB
  int tid = threadIdx.x; int p = blockIdx.x;     // 128 blocks
  float w[9];
  #pragma unroll
  for (int i = 0; i < 9; i++) w[i] = rfl(scw[i]);
  float bias = rfl(scb[0]);
  const float* src = in + (size_t)p*6889;
  for (int k = tid; k < 6889; k += 256) buf[k] = src[k];
  __syncthreads();
  const int HIN[4] = {83,28,10,4}, HOUT[4] = {28,10,4,2};
  const int OIN[4] = {0, 6889, 6889+784, 6889+784+100};
  const size_t GOFF[4] = {P_D2, P_D3, P_D4, P_D5};
  #pragma unroll
  for (int st = 0; st < 4; st++) {
    const int hin = HIN[st], hout = HOUT[st];
    const float* bi = buf + OIN[st];
    float* bo = buf + OIN[st] + hin*hin;
    float* go = ws + GOFF[st] + (size_t)p*(hout*hout);
    for (int k = tid; k < hout*hout; k += 256) {
      int i = k/hout, j = k - i*hout;
      float s = bias;
      #pragma unroll
      for (int u = 0; u < 3; u++) {
        int r = 3*i - 1 + u;
        if ((unsigned)r < (unsigned)hin) {
          #pragma unroll
          for (int v = 0; v < 3; v++) {
            int cc = 3*j - 1 + v;
            if ((unsigned)cc < (unsigned)hin) s += bi[r*hin + cc]*w[u*3+v];
          }
        }
      }
      bo[k] = s; go[k] = s;
    }
    __syncthreads();
  }
}

// ---------------- pyramid: branch-split waves, 4x4 outputs/thread ----------------
// 512 threads: tid<256 -> branch A, >=256 -> branch B (wave-uniform). Shared hrow
// staged once per block (64x64 output tile). Each thread: 4w x 4h outputs; streams
// 8 z-rows/level, each y-lerped once and folded into up to 4 output rows.
// hrow rows bank-rotated by (row&3)*8 floats to break same-phase conflicts.
__global__ __launch_bounds__(512) void k_accum(const float* __restrict__ ws,
                                               const float* __restrict__ iaw,
                                               const float* __restrict__ ibw,
                                               float* __restrict__ score) {
  __shared__ __align__(16) float hrow[4320];  // 43 rows x 96 + 2 zero rows x 96
  int tid = threadIdx.x;
  int c = blockIdx.y, b = blockIdx.z;
  int tx0 = (blockIdx.x & 3)*64, ty0 = (blockIdx.x >> 2)*64;
  int half = tid >> 8;                         // 0 = branch A, 1 = branch B
  int t2 = tid & 255;
  int lx4 = (t2 & 15)*4, lyt = t2 >> 4;        // 16x16 threads, 4w x 4h px each

  const float* wp = half ? ibw : iaw;
  float w[25];
  #pragma unroll
  for (int i = 0; i < 25; i++) w[i] = wp[i];
  float s_ = ws[1184 + half*64 + c];
  float C_ = ws[1216 + half*64 + c];

  const int NS[5]  = {83,28,10,4,2};
  const int HBF[5] = {0, 24*96, 33*96, 38*96, 41*96};
  const int ZROW = 43*96;
  const size_t OFF[5] = {P_D1,P_D2,P_D3,P_D4,P_D5};

  // ---- staging: x-lerped rows for all 5 levels + zero rows, ONE barrier ----
  for (int k = tid; k < 192; k += 512) hrow[ZROW + k] = 0.f;
  #pragma unroll
  for (int lvl = 0; lvl < 5; lvl++) {
    const int n = NS[lvl];
    const float inv = (float)n * (1.f/256.f);
    float f0 = ((float)(ty0-2)+0.5f)*inv - 0.5f;
    float f1 = ((float)(ty0+65)+0.5f)*inv - 0.5f;
    int yb0 = min(max((int)floorf(f0),0), n-2);
    int yb1 = min(max((int)floorf(f1),0), n-2);
    int rows = yb1 - yb0 + 2;
    const float* dp = ws + OFF[lvl] + (size_t)(b*32+c)*(n*n);
    for (int k = tid; k < rows*68; k += 512) {
      int r = k/68, zx = k - r*68;
      int gx = tx0 + zx - 2;
      float h = 0.f;
      if ((unsigned)gx < 256u) {
        float f = ((float)gx + 0.5f)*inv - 0.5f;
        float ff = floorf(f);
        int i0 = (int)ff;
        int xb = min(max(i0,0), n-2);
        float wx = (i0 < 0) ? 0.f : (i0 > n-2 ? 1.f : f - ff);
        const float* rp = dp + (yb0 + r)*n + xb;
        h = rp[0] + wx*(rp[1] - rp[0]);
      }
      hrow[HBF[lvl] + r*96 + ((r&3)<<3) + zx] = h;   // bank-rotated row
    }
  }
  __syncthreads();                             // the ONLY barrier

  // ---- compute: 16 outputs/thread, one branch ----
  float acc[16];
  #pragma unroll
  for (int i = 0; i < 16; i++) acc[i] = 0.f;
  int gy0 = ty0 + 4*lyt - 2;
  #pragma unroll
  for (int lvl = 0; lvl < 5; lvl++) {
    const int n = NS[lvl];
    const float inv = (float)n * (1.f/256.f);
    float f0u = ((float)(ty0-2)+0.5f)*inv - 0.5f;
    int yb0 = min(max((int)floorf(f0u),0), n-2);         // uniform -> SGPR
    float cc[4][4];
    #pragma unroll
    for (int p = 0; p < 4; p++)
      #pragma unroll
      for (int j = 0; j < 4; j++) cc[p][j] = 0.f;
    #pragma unroll
    for (int zr = 0; zr < 8; zr++) {
      int gy = gy0 + zr;
      float f = ((float)gy + 0.5f)*inv - 0.5f;
      float ff = floorf(f);
      int i0 = (int)ff;
      int yb = min(max(i0,0), n-2);
      float wy = (i0 < 0) ? 0.f : (i0 > n-2 ? 1.f : f - ff);
      bool valid = ((unsigned)gy < 256u);
      int r0 = yb - yb0;
      int offa = HBF[lvl] + r0*96 + ((r0&3)<<3) + lx4;
      int offb = HBF[lvl] + (r0+1)*96 + (((r0+1)&3)<<3) + lx4;
      offa = valid ? offa : (ZROW + lx4);
      offb = valid ? offb : (ZROW + 96 + lx4);
      wy = valid ? wy : 0.f;
      float4 a0 = *(const float4*)&hrow[offa];
      float4 a1 = *(const float4*)&hrow[offa+4];
      float4 b0 = *(const float4*)&hrow[offb];
      float4 b1 = *(const float4*)&hrow[offb+4];
      float z[8];
      z[0] = a0.x + wy*(b0.x - a0.x);
      z[1] = a0.y + wy*(b0.y - a0.y);
      z[2] = a0.z + wy*(b0.z - a0.z);
      z[3] = a0.w + wy*(b0.w - a0.w);
      z[4] = a1.x + wy*(b1.x - a1.x);
      z[5] = a1.y + wy*(b1.y - a1.y);
      z[6] = a1.z + wy*(b1.z - a1.z);
      z[7] = a1.w + wy*(b1.w - a1.w);
      #pragma unroll
      for (int p = 0; p < 4; p++) {
        int r = zr - p;
        if (r >= 0 && r < 5) {
          #pragma unroll
          for (int j = 0; j < 4; j++)
            #pragma unroll
            for (int v = 0; v < 5; v++)
              cc[p][j] += z[j+v]*w[r*5+v];
        }
      }
    }
    #pragma unroll
    for (int p = 0; p < 4; p++)
      #pragma unroll
      for (int j = 0; j < 4; j++) {
        float v = cc[p][j]*s_ + C_;
        acc[p*4+j] += (v >= 0.f) ? v : 0.01f*v;
      }
  }
  int oy = ty0 + 4*lyt, ox = tx0 + lx4;
  size_t base = ((size_t)(b*64 + half*32 + c)*256 + oy)*256 + ox;
  #pragma unroll
  for (int p = 0; p < 4; p++)
    *(float4*)&score[base + (size_t)p*256] = make_float4(acc[p*4],acc[p*4+1],acc[p*4+2],acc[p*4+3]);
}

// ---------------- ft pass: BN -> MaxLeakyReLU -> BN -> EmphaseLocal ----------------
__global__ __launch_bounds__(256) void k_ft(const float* __restrict__ in,
                                            float* __restrict__ out,
                                            const float* __restrict__ P, float scale) {
  __shared__ float A[74*77];   // pointwise(y) with halo 5; stride 77 (conflict fix)
  __shared__ float Bf[64*77];  // vertical 11-sums
  int tid = threadIdx.x;
  int c = blockIdx.y, b = blockIdx.z;
  int ty0 = (blockIdx.x >> 2)*64, tx0 = (blockIdx.x & 3)*64;
  float fs1 = rfl(P[1312+c]), fc1 = rfl(P[1376+c]), fs2 = rfl(P[1440+c]), fc2 = rfl(P[1504+c]);
  const float* ip = in + (size_t)(b*64 + c)*65536;
  for (int k = tid; k < 1480; k += 256) {        // 74 rows x 20 aligned float4
    int ay = k/20, qx = k - ay*20;
    int gy = ty0 + ay - 5;
    int gx0 = tx0 - 8 + qx*4;
    float4 v = make_float4(0.f,0.f,0.f,0.f);
    bool rowok = ((unsigned)gy < 256u);
    if (rowok) {
      if (gx0 >= 0 && gx0 <= 252) v = *(const float4*)(ip + gy*256 + gx0);
      else {
        float* pv = (float*)&v;
        #pragma unroll
        for (int e = 0; e < 4; e++) { int gx = gx0+e; if ((unsigned)gx < 256u) pv[e] = ip[gy*256 + gx]; }
      }
    }
    float* pv = (float*)&v;
    int ax0 = gx0 - tx0 + 5;
    #pragma unroll
    for (int e = 0; e < 4; e++) {
      int ax = ax0 + e;
      if ((unsigned)ax < 74u) {
        int gx = gx0 + e;
        float y = 0.f;
        if (rowok && (unsigned)gx < 256u) {
          float t = pv[e]*fs1 + fc1;
          t = (t > 0.1f) ? t : 0.7f*t;
          y = t*fs2 + fc2;
        }
        A[ay*77 + ax] = y;
      }
    }
  }
  __syncthreads();
  for (int task = tid; task < 296; task += 256) {   // 74 cols x 4 chunks of 16 rows
    int chunk = task/74; int col = task - chunk*74;
    int r0 = chunk*16;
    float s = 0.f;
    #pragma unroll
    for (int u = 0; u < 11; u++) s += A[(r0+u)*77 + col];
    Bf[r0*77 + col] = s;
    #pragma unroll
    for (int r = 1; r < 16; r++) {
      s += A[(r0+r+10)*77 + col] - A[(r0+r-1)*77 + col];
      Bf[(r0+r)*77 + col] = s;
    }
  }
  __syncthreads();
  {
    int r = tid >> 2; int c0 = (tid & 3)*16;        // 64 rows x 4 chunks of 16 cols
    float s = 0.f;
    #pragma unroll
    for (int v = 0; v < 11; v++) s += Bf[r*77 + c0 + v];
    float* op = out + (size_t)(b*64 + c)*65536 + (size_t)(ty0+r)*256 + tx0;
    float4 bufv;
    #pragma unroll
    for (int j = 0; j < 16; j++) {
      float mean = s*(1.f/121.f);
      float y = A[(r+5)*77 + c0 + j + 5];
      float sig = 1.f/(1.f + __expf(-(y - mean)));
      ((float*)&bufv)[j & 3] = y*sig*scale;
      if ((j & 3) == 3) *(float4*)(op + c0 + (j & ~3)) = bufv;
      if (j < 15) s += Bf[r*77 + c0 + j + 11] - Bf[r*77 + c0 + j];
    }
  }
}

// ---------------- launch ----------------
extern "C" void kernel_launch(void* const* d_in, const int* in_sizes, int n_in,
                              void* d_out, int out_size, void* d_ws, size_t ws_size,
                              hipStream_t stream) {
  const float* x = (const float*)d_in[0];
  float* ws = (float*)d_ws;
  float* out = (float*)d_out;

  PrepArgs pa;
  for (int i = 0; i < 39; i++) pa.p[i] = (const float*)d_in[i];
  k_prep<<<dim3(1), dim3(256), 0, stream>>>(pa, ws);

  k_mode_mlp<<<dim3(16,16,4), dim3(16,16), 0, stream>>>(x, ws, ws + P_D);

  const float* scw = (const float*)d_in[17];
  const float* scb = (const float*)d_in[18];
  {
    int total = 128*83*83;
    k_down<<<dim3((total+255)/256), dim3(256), 0, stream>>>(ws + P_D, ws + P_D1, scw, scb);
  }
  k_down_rest<<<dim3(128), dim3(256), 0, stream>>>(ws + P_D1, ws, scw, scb);

  k_accum<<<dim3(16,32,4), dim3(512), 0, stream>>>(ws, (const float*)d_in[19],
                                                   (const float*)d_in[25], ws + P_SCORE);

  // ft x3, ping-pong ws_score <-> d_out; /5 folded into last pass
  k_ft<<<dim3(16,64,4), dim3(256), 0, stream>>>(ws + P_SCORE, out, ws, 1.f);
  k_ft<<<dim3(16,64,4), dim3(256), 0, stream>>>(out, ws + P_SCORE, ws, 1.f);
  k_ft<<<dim3(16,64,4), dim3(256), 0, stream>>>(ws + P_SCORE, out, ws, 0.2f);
}

// Round 8
// 600.975 us; speedup vs baseline: 3.6609x; 1.0119x over previous
//
#include <hip/hip_runtime.h>
#include <math.h>

#define EPSI 1e-5f

// ---------------- workspace layout (floats) ----------------
//   A1[96] @0, C1[32] @96, A2[1024] @128, C2[32] @1152,
//   sa[32] @1184, Ca[32] @1216, sb[32] @1248, Cb[32] @1280,
//   fs1[64] @1312, fc1[64] @1376, fs2[64] @1440, fc2[64] @1504
#define P_D1 2048                    // 128*83*83 = 881792
#define P_D2 (P_D1 + 128*83*83)
#define P_D3 (P_D2 + 128*28*28)
#define P_D4 (P_D3 + 128*10*10)
#define P_D5 (P_D4 + 128*4*4)
#define P_SCORE (P_D5 + 128*2*2)     // 4*64*256*256 = 16777216 floats
#define P_D  P_SCORE                 // d (4,32,248,248) aliases score head (dead before accum)

__device__ __forceinline__ float rfl(float x) {
  return __builtin_bit_cast(float, __builtin_amdgcn_readfirstlane(__builtin_bit_cast(int, x)));
}

struct PrepArgs { const float* p[39]; };

// ---------------- prep: fold all affine params ----------------
__global__ void k_prep(PrepArgs a, float* __restrict__ P) {
  int t = threadIdx.x;
  const float *w1=a.p[1],*b1=a.p[2],*w2=a.p[3],*b2=a.p[4],*g1=a.p[5],*bb1=a.p[6],*m1=a.p[7],*v1=a.p[8];
  const float *w3=a.p[9],*b3=a.p[10],*w4=a.p[11],*b4=a.p[12],*g2=a.p[13],*bb2=a.p[14],*m2=a.p[15],*v2=a.p[16];
  for (int i=t;i<96;i+=256){ int o=i/3; float s=g1[o]/sqrtf(v1[o]+EPSI); P[i]=w1[i]*w2[o]*s; }
  for (int o=t;o<32;o+=256){ float s=g1[o]/sqrtf(v1[o]+EPSI); P[96+o]=(b1[o]*w2[o]+b2[o]-m1[o])*s+bb1[o]; }
  for (int i=t;i<1024;i+=256){ int o2=i/32; float s=g2[o2]/sqrtf(v2[o2]+EPSI); P[128+i]=w3[i]*w4[o2]*s; }
  for (int o=t;o<32;o+=256){ float s=g2[o]/sqrtf(v2[o]+EPSI); P[1152+o]=(b3[o]*w4[o]+b4[o]-m2[o])*s+bb2[o]; }
  const float *iag=a.p[21],*iab=a.p[22],*iam=a.p[23],*iav=a.p[24],*iabias=a.p[20];
  for (int c=t;c<32;c+=256){ float s=iag[c]/sqrtf(iav[c]+EPSI); P[1184+c]=s; P[1216+c]=(iabias[0]-iam[c])*s+iab[c]; }
  const float *ibg=a.p[27],*ibb=a.p[28],*ibm=a.p[29],*ibv=a.p[30],*ibbias=a.p[26];
  for (int c=t;c<32;c+=256){ float s=ibg[c]/sqrtf(ibv[c]+EPSI); P[1248+c]=s; P[1280+c]=(ibbias[0]-ibm[c])*s+ibb[c]; }
  const float *f1g=a.p[31],*f1b=a.p[32],*f1m=a.p[33],*f1v=a.p[34];
  for (int c=t;c<64;c+=256){ float s=f1g[c]/sqrtf(f1v[c]+EPSI); P[1312+c]=s; P[1376+c]=f1b[c]-f1m[c]*s; }
  const float *f2g=a.p[35],*f2b=a.p[36],*f2m=a.p[37],*f2v=a.p[38];
  for (int c=t;c<64;c+=256){ float s=f2g[c]/sqrtf(f2v[c]+EPSI); P[1440+c]=s; P[1504+c]=f2b[c]-f2m[c]*s; }
}

// ---------------- quantize + mode-pool(11,1,1) + fused 3->32->32 MLP ----------------
__global__ __launch_bounds__(256) void k_mode_mlp(const float* __restrict__ x,
                                                 const float* __restrict__ P,
                                                 float* __restrict__ dout) {
  __shared__ int qs[3*676];  // 3 channels, 26x26 levels
  int lx = threadIdx.x, ly = threadIdx.y;
  int tid = ly*16 + lx;
  int tx0 = blockIdx.x*16, ty0 = blockIdx.y*16;
  int b = blockIdx.z;
  for (int k = tid; k < 3*676; k += 256) {
    int cch = k/676; int rem = k - cch*676; int r = rem/26; int cc = rem - r*26;
    int gy = ty0 + r - 1, gx = tx0 + cc - 1;
    int q = 0;
    if ((unsigned)gy < 256u && (unsigned)gx < 256u) {
      float v = x[((size_t)(b*3+cch)*256 + gy)*256 + gx];
      q = (int)rintf(v*255.0f/16.0f);
      q = q < 0 ? 0 : (q > 16 ? 16 : q);
    }
    qs[k] = q;
  }
  __syncthreads();
  int oi = ty0 + ly, oj = tx0 + lx;
  if (oi >= 248 || oj >= 248) return;

  float md[3];
  #pragma unroll
  for (int cch = 0; cch < 3; cch++) {
    const int* qp = &qs[cch*676 + ly*26 + lx];
    unsigned h0=0,h1=0,h2=0,h3=0,h4=0;
    #pragma unroll 1
    for (int u = 0; u < 11; u++) {
      #pragma unroll
      for (int v = 0; v < 11; v++) {
        int q = qp[u*26 + v];
        unsigned inc = 1u << ((q & 3) << 3);
        int sel = q >> 2;
        h0 += (sel==0) ? inc : 0u;
        h1 += (sel==1) ? inc : 0u;
        h2 += (sel==2) ? inc : 0u;
        h3 += (sel==3) ? inc : 0u;
        h4 += (sel==4) ? inc : 0u;
      }
    }
    int best = -1, mode = 0;
    #define CHK(l, w) { int cnt = (int)((w >> (((l)&3)*8)) & 255u); if (cnt > best) { best = cnt; mode = (l); } }
    CHK(0,h0) CHK(1,h0) CHK(2,h0) CHK(3,h0)
    CHK(4,h1) CHK(5,h1) CHK(6,h1) CHK(7,h1)
    CHK(8,h2) CHK(9,h2) CHK(10,h2) CHK(11,h2)
    CHK(12,h3) CHK(13,h3) CHK(14,h3) CHK(15,h3)
    CHK(16,h4)
    #undef CHK
    md[cch] = (float)mode * 0.0625f;
  }

  const float* A1 = P;           const float* C1 = P + 96;
  const float* A2 = P + 128;     const float* C2 = P + 1152;
  float h[32];
  #pragma unroll
  for (int o = 0; o < 32; o++) {
    float v = C1[o] + A1[o*3]*md[0] + A1[o*3+1]*md[1] + A1[o*3+2]*md[2];
    h[o] = (v >= 0.f) ? v : 0.01f*v;
  }
  size_t ob = ((size_t)(b*32)*248 + oi)*248 + oj;
  #pragma unroll
  for (int o2 = 0; o2 < 32; o2++) {
    float acc = C2[o2];
    #pragma unroll
    for (int o = 0; o < 32; o++) acc += A2[o2*32+o]*h[o];
    acc = (acc >= 0.f) ? acc : 0.01f*acc;
    dout[ob + (size_t)o2*(248*248)] = acc;
  }
}

// ---------------- shared 3x3 conv, stride 3, pad 1 (248 -> 83) ----------------
__global__ void k_down(const float* __restrict__ in, float* __restrict__ out,
                       const float* __restrict__ scw, const float* __restrict__ scb) {
  const int Hin = 248, Hout = 83, total = 128*83*83;
  int idx = blockIdx.x*256 + threadIdx.x;
  if (idx >= total) return;
  float w[9];
  #pragma unroll
  for (int i = 0; i < 9; i++) w[i] = rfl(scw[i]);
  float bias = rfl(scb[0]);
  int j = idx % Hout; int t2 = idx / Hout; int i = t2 % Hout; int p = t2 / Hout;
  const float* base = in + (size_t)p*Hin*Hin;
  float s = bias;
  #pragma unroll
  for (int u = 0; u < 3; u++) {
    int r = 3*i - 1 + u;
    if ((unsigned)r < (unsigned)Hin) {
      #pragma unroll
      for (int v = 0; v < 3; v++) {
        int cc = 3*j - 1 + v;
        if ((unsigned)cc < (unsigned)Hin) s += base[(size_t)r*Hin + cc]*w[u*3+v];
      }
    }
  }
  out[idx] = s;
}

// ---------------- merged tail downsamples: 83->28->10->4->2, one block per (b,c) ----------------
__global__ __launch_bounds__(256) void k_down_rest(const float* __restrict__ in, float* __restrict__ ws,
                                                   const float* __restrict__ scw, const float* __restrict__ scb) {
  __shared__ float buf[6889 + 784 + 100 + 16];   // 31.2 KB
  int tid = threadIdx.x; int p = blockIdx.x;     // 128 blocks
  float w[9];
  #pragma unroll
  for (int i = 0; i < 9; i++) w[i] = rfl(scw[i]);
  float bias = rfl(scb[0]);
  const float* src = in + (size_t)p*6889;
  for (int k = tid; k < 6889; k += 256) buf[k] = src[k];
  __syncthreads();
  const int HIN[4] = {83,28,10,4}, HOUT[4] = {28,10,4,2};
  const int OIN[4] = {0, 6889, 6889+784, 6889+784+100};
  const size_t GOFF[4] = {P_D2, P_D3, P_D4, P_D5};
  #pragma unroll
  for (int st = 0; st < 4; st++) {
    const int hin = HIN[st], hout = HOUT[st];
    const float* bi = buf + OIN[st];
    float* bo = buf + OIN[st] + hin*hin;
    float* go = ws + GOFF[st] + (size_t)p*(hout*hout);
    for (int k = tid; k < hout*hout; k += 256) {
      int i = k/hout, j = k - i*hout;
      float s = bias;
      #pragma unroll
      for (int u = 0; u < 3; u++) {
        int r = 3*i - 1 + u;
        if ((unsigned)r < (unsigned)hin) {
          #pragma unroll
          for (int v = 0; v < 3; v++) {
            int cc = 3*j - 1 + v;
            if ((unsigned)cc < (unsigned)hin) s += bi[r*hin + cc]*w[u*3+v];
          }
        }
      }
      bo[k] = s; go[k] = s;
    }
    __syncthreads();
  }
}

// ---------------- pyramid: branch-split within 256-thread block, 4x4 outputs/thread ----------------
// Block = 256 threads, 64(w) x 32(h) output tile, grid 4096. tid<128 -> branch A,
// >=128 -> branch B (wave-uniform). 16x8 threads per branch, 4x4 px each.
// Weights (25) + scale/bias per branch forced to SGPRs via readfirstlane (27 scalars
// fits the SGPR file; R6's 54 did not). hrow staged once (ONE barrier), rows
// bank-rotated by (r&3)*8. No launch_bounds cap beyond 256 (R7's 512 capped VGPR=128
// and spilled 400MB/dispatch to scratch).
__global__ __launch_bounds__(256) void k_accum(const float* __restrict__ ws,
                                               const float* __restrict__ iaw,
                                               const float* __restrict__ ibw,
                                               float* __restrict__ score) {
  __shared__ __align__(16) float hrow[3072];  // 30 rows x 96 + 2 zero rows x 96
  int tid = threadIdx.x;
  int c = blockIdx.y, b = blockIdx.z;
  int tx0 = (blockIdx.x & 3)*64, ty0 = (blockIdx.x >> 2)*32;
  int half = tid >> 7;                         // 0 = branch A, 1 = branch B
  int t2 = tid & 127;
  int lx4 = (t2 & 15)*4, lyt = t2 >> 4;        // 16x8 threads, 4w x 4h px each

  const float* wp = half ? ibw : iaw;
  float w[25];
  #pragma unroll
  for (int i = 0; i < 25; i++) w[i] = rfl(wp[i]);
  float s_ = rfl(ws[1184 + half*64 + c]);
  float C_ = rfl(ws[1216 + half*64 + c]);

  const int NS[5]  = {83,28,10,4,2};
  const int HBF[5] = {0, 14*96, 21*96, 25*96, 28*96};
  const int ZROW = 30*96;
  const size_t OFF[5] = {P_D1,P_D2,P_D3,P_D4,P_D5};

  // ---- staging: x-lerped rows for all 5 levels + zero rows, ONE barrier ----
  for (int k = tid; k < 192; k += 256) hrow[ZROW + k] = 0.f;
  #pragma unroll
  for (int lvl = 0; lvl < 5; lvl++) {
    const int n = NS[lvl];
    const float inv = (float)n * (1.f/256.f);
    float f0 = ((float)(ty0-2)+0.5f)*inv - 0.5f;
    float f1 = ((float)(ty0+33)+0.5f)*inv - 0.5f;
    int yb0 = min(max((int)floorf(f0),0), n-2);
    int yb1 = min(max((int)floorf(f1),0), n-2);
    int rows = yb1 - yb0 + 2;
    const float* dp = ws + OFF[lvl] + (size_t)(b*32+c)*(n*n);
    for (int k = tid; k < rows*68; k += 256) {
      int r = k/68, zx = k - r*68;
      int gx = tx0 + zx - 2;
      float h = 0.f;
      if ((unsigned)gx < 256u) {
        float f = ((float)gx + 0.5f)*inv - 0.5f;
        float ff = floorf(f);
        int i0 = (int)ff;
        int xb = min(max(i0,0), n-2);
        float wx = (i0 < 0) ? 0.f : (i0 > n-2 ? 1.f : f - ff);
        const float* rp = dp + (yb0 + r)*n + xb;
        h = rp[0] + wx*(rp[1] - rp[0]);
      }
      hrow[HBF[lvl] + r*96 + ((r&3)<<3) + zx] = h;   // bank-rotated row
    }
  }
  __syncthreads();                             // the ONLY barrier

  // ---- compute: 16 outputs/thread, one branch ----
  float acc[16];
  #pragma unroll
  for (int i = 0; i < 16; i++) acc[i] = 0.f;
  int gy0 = ty0 + 4*lyt - 2;
  #pragma unroll
  for (int lvl = 0; lvl < 5; lvl++) {
    const int n = NS[lvl];
    const float inv = (float)n * (1.f/256.f);
    float f0u = ((float)(ty0-2)+0.5f)*inv - 0.5f;
    int yb0 = min(max((int)floorf(f0u),0), n-2);         // uniform -> SGPR
    float cc[4][4];
    #pragma unroll
    for (int p = 0; p < 4; p++)
      #pragma unroll
      for (int j = 0; j < 4; j++) cc[p][j] = 0.f;
    #pragma unroll
    for (int zr = 0; zr < 8; zr++) {
      int gy = gy0 + zr;
      float f = ((float)gy + 0.5f)*inv - 0.5f;
      float ff = floorf(f);
      int i0 = (int)ff;
      int yb = min(max(i0,0), n-2);
      float wy = (i0 < 0) ? 0.f : (i0 > n-2 ? 1.f : f - ff);
      bool valid = ((unsigned)gy < 256u);
      int r0 = yb - yb0;
      int offa = HBF[lvl] + r0*96 + ((r0&3)<<3) + lx4;
      int offb = HBF[lvl] + (r0+1)*96 + (((r0+1)&3)<<3) + lx4;
      offa = valid ? offa : (ZROW + lx4);
      offb = valid ? offb : (ZROW + 96 + lx4);
      wy = valid ? wy : 0.f;
      float4 a0 = *(const float4*)&hrow[offa];
      float4 a1 = *(const float4*)&hrow[offa+4];
      float4 b0 = *(const float4*)&hrow[offb];
      float4 b1 = *(const float4*)&hrow[offb+4];
      float z[8];
      z[0] = a0.x + wy*(b0.x - a0.x);
      z[1] = a0.y + wy*(b0.y - a0.y);
      z[2] = a0.z + wy*(b0.z - a0.z);
      z[3] = a0.w + wy*(b0.w - a0.w);
      z[4] = a1.x + wy*(b1.x - a1.x);
      z[5] = a1.y + wy*(b1.y - a1.y);
      z[6] = a1.z + wy*(b1.z - a1.z);
      z[7] = a1.w + wy*(b1.w - a1.w);
      #pragma unroll
      for (int p = 0; p < 4; p++) {
        int r = zr - p;
        if (r >= 0 && r < 5) {
          #pragma unroll
          for (int j = 0; j < 4; j++)
            #pragma unroll
            for (int v = 0; v < 5; v++)
              cc[p][j] += z[j+v]*w[r*5+v];
        }
      }
    }
    #pragma unroll
    for (int p = 0; p < 4; p++)
      #pragma unroll
      for (int j = 0; j < 4; j++) {
        float v = cc[p][j]*s_ + C_;
        acc[p*4+j] += (v >= 0.f) ? v : 0.01f*v;
      }
  }
  int oy = ty0 + 4*lyt, ox = tx0 + lx4;
  size_t base = ((size_t)(b*64 + half*32 + c)*256 + oy)*256 + ox;
  #pragma unroll
  for (int p = 0; p < 4; p++)
    *(float4*)&score[base + (size_t)p*256] = make_float4(acc[p*4],acc[p*4+1],acc[p*4+2],acc[p*4+3]);
}

// ---------------- ft pass: BN -> MaxLeakyReLU -> BN -> EmphaseLocal ----------------
__global__ __launch_bounds__(256) void k_ft(const float* __restrict__ in,
                                            float* __restrict__ out,
                                            const float* __restrict__ P, float scale) {
  __shared__ float A[74*77];   // pointwise(y) with halo 5; stride 77 (conflict fix)
  __shared__ float Bf[64*77];  // vertical 11-sums
  int tid = threadIdx.x;
  int c = blockIdx.y, b = blockIdx.z;
  int ty0 = (blockIdx.x >> 2)*64, tx0 = (blockIdx.x & 3)*64;
  float fs1 = rfl(P[1312+c]), fc1 = rfl(P[1376+c]), fs2 = rfl(P[1440+c]), fc2 = rfl(P[1504+c]);
  const float* ip = in + (size_t)(b*64 + c)*65536;
  for (int k = tid; k < 1480; k += 256) {        // 74 rows x 20 aligned float4
    int ay = k/20, qx = k - ay*20;
    int gy = ty0 + ay - 5;
    int gx0 = tx0 - 8 + qx*4;
    float4 v = make_float4(0.f,0.f,0.f,0.f);
    bool rowok = ((unsigned)gy < 256u);
    if (rowok) {
      if (gx0 >= 0 && gx0 <= 252) v = *(const float4*)(ip + gy*256 + gx0);
      else {
        float* pv = (float*)&v;
        #pragma unroll
        for (int e = 0; e < 4; e++) { int gx = gx0+e; if ((unsigned)gx < 256u) pv[e] = ip[gy*256 + gx]; }
      }
    }
    float* pv = (float*)&v;
    int ax0 = gx0 - tx0 + 5;
    #pragma unroll
    for (int e = 0; e < 4; e++) {
      int ax = ax0 + e;
      if ((unsigned)ax < 74u) {
        int gx = gx0 + e;
        float y = 0.f;
        if (rowok && (unsigned)gx < 256u) {
          float t = pv[e]*fs1 + fc1;
          t = (t > 0.1f) ? t : 0.7f*t;
          y = t*fs2 + fc2;
        }
        A[ay*77 + ax] = y;
      }
    }
  }
  __syncthreads();
  for (int task = tid; task < 296; task += 256) {   // 74 cols x 4 chunks of 16 rows
    int chunk = task/74; int col = task - chunk*74;
    int r0 = chunk*16;
    float s = 0.f;
    #pragma unroll
    for (int u = 0; u < 11; u++) s += A[(r0+u)*77 + col];
    Bf[r0*77 + col] = s;
    #pragma unroll
    for (int r = 1; r < 16; r++) {
      s += A[(r0+r+10)*77 + col] - A[(r0+r-1)*77 + col];
      Bf[(r0+r)*77 + col] = s;
    }
  }
  __syncthreads();
  {
    int r = tid >> 2; int c0 = (tid & 3)*16;        // 64 rows x 4 chunks of 16 cols
    float s = 0.f;
    #pragma unroll
    for (int v = 0; v < 11; v++) s += Bf[r*77 + c0 + v];
    float* op = out + (size_t)(b*64 + c)*65536 + (size_t)(ty0+r)*256 + tx0;
    float4 bufv;
    #pragma unroll
    for (int j = 0; j < 16; j++) {
      float mean = s*(1.f/121.f);
      float y = A[(r+5)*77 + c0 + j + 5];
      float sig = 1.f/(1.f + __expf(-(y - mean)));
      ((float*)&bufv)[j & 3] = y*sig*scale;
      if ((j & 3) == 3) *(float4*)(op + c0 + (j & ~3)) = bufv;
      if (j < 15) s += Bf[r*77 + c0 + j + 11] - Bf[r*77 + c0 + j];
    }
  }
}

// ---------------- launch ----------------
extern "C" void kernel_launch(void* const* d_in, const int* in_sizes, int n_in,
                              void* d_out, int out_size, void* d_ws, size_t ws_size,
                              hipStream_t stream) {
  const float* x = (const float*)d_in[0];
  float* ws = (float*)d_ws;
  float* out = (float*)d_out;

  PrepArgs pa;
  for (int i = 0; i < 39; i++) pa.p[i] = (const float*)d_in[i];
  k_prep<<<dim3(1), dim3(256), 0, stream>>>(pa, ws);

  k_mode_mlp<<<dim3(16,16,4), dim3(16,16), 0, stream>>>(x, ws, ws + P_D);

  const float* scw = (const float*)d_in[17];
  const float* scb = (const float*)d_in[18];
  {
    int total = 128*83*83;
    k_down<<<dim3((total+255)/256), dim3(256), 0, stream>>>(ws + P_D, ws + P_D1, scw, scb);
  }
  k_down_rest<<<dim3(128), dim3(256), 0, stream>>>(ws + P_D1, ws, scw, scb);

  k_accum<<<dim3(32,32,4), dim3(256), 0, stream>>>(ws, (const float*)d_in[19],
                                                   (const float*)d_in[25], ws + P_SCORE);

  // ft x3, ping-pong ws_score <-> d_out; /5 folded into last pass
  k_ft<<<dim3(16,64,4), dim3(256), 0, stream>>>(ws + P_SCORE, out, ws, 1.f);
  k_ft<<<dim3(16,64,4), dim3(256), 0, stream>>>(out, ws + P_SCORE, ws, 1.f);
  k_ft<<<dim3(16,64,4), dim3(256), 0, stream>>>(ws + P_SCORE, out, ws, 0.2f);
}

// Round 9
// 508.261 us; speedup vs baseline: 4.3287x; 1.1824x over previous
//
#include <hip/hip_runtime.h>
#include <math.h>

#define EPSI 1e-5f

// ---------------- workspace layout (floats) ----------------
//   A1[96] @0, C1[32] @96, A2[1024] @128, C2[32] @1152,
//   sa[32] @1184, Ca[32] @1216, sb[32] @1248, Cb[32] @1280,
//   fs1[64] @1312, fc1[64] @1376, fs2[64] @1440, fc2[64] @1504
#define P_D1 2048                    // 128*83*83 = 881792
#define P_D2 (P_D1 + 128*83*83)
#define P_D3 (P_D2 + 128*28*28)
#define P_D4 (P_D3 + 128*10*10)
#define P_D5 (P_D4 + 128*4*4)
#define P_SCORE (P_D5 + 128*2*2)     // 4*64*256*256 = 16777216 floats
#define P_D  P_SCORE                 // d (4,32,248,248) aliases score head (dead before accum)

__device__ __forceinline__ float rfl(float x) {
  return __builtin_bit_cast(float, __builtin_amdgcn_readfirstlane(__builtin_bit_cast(int, x)));
}

struct PrepArgs { const float* p[39]; };

// ---------------- prep: fold all affine params ----------------
__global__ void k_prep(PrepArgs a, float* __restrict__ P) {
  int t = threadIdx.x;
  const float *w1=a.p[1],*b1=a.p[2],*w2=a.p[3],*b2=a.p[4],*g1=a.p[5],*bb1=a.p[6],*m1=a.p[7],*v1=a.p[8];
  const float *w3=a.p[9],*b3=a.p[10],*w4=a.p[11],*b4=a.p[12],*g2=a.p[13],*bb2=a.p[14],*m2=a.p[15],*v2=a.p[16];
  for (int i=t;i<96;i+=256){ int o=i/3; float s=g1[o]/sqrtf(v1[o]+EPSI); P[i]=w1[i]*w2[o]*s; }
  for (int o=t;o<32;o+=256){ float s=g1[o]/sqrtf(v1[o]+EPSI); P[96+o]=(b1[o]*w2[o]+b2[o]-m1[o])*s+bb1[o]; }
  for (int i=t;i<1024;i+=256){ int o2=i/32; float s=g2[o2]/sqrtf(v2[o2]+EPSI); P[128+i]=w3[i]*w4[o2]*s; }
  for (int o=t;o<32;o+=256){ float s=g2[o]/sqrtf(v2[o]+EPSI); P[1152+o]=(b3[o]*w4[o]+b4[o]-m2[o])*s+bb2[o]; }
  const float *iag=a.p[21],*iab=a.p[22],*iam=a.p[23],*iav=a.p[24],*iabias=a.p[20];
  for (int c=t;c<32;c+=256){ float s=iag[c]/sqrtf(iav[c]+EPSI); P[1184+c]=s; P[1216+c]=(iabias[0]-iam[c])*s+iab[c]; }
  const float *ibg=a.p[27],*ibb=a.p[28],*ibm=a.p[29],*ibv=a.p[30],*ibbias=a.p[26];
  for (int c=t;c<32;c+=256){ float s=ibg[c]/sqrtf(ibv[c]+EPSI); P[1248+c]=s; P[1280+c]=(ibbias[0]-ibm[c])*s+ibb[c]; }
  const float *f1g=a.p[31],*f1b=a.p[32],*f1m=a.p[33],*f1v=a.p[34];
  for (int c=t;c<64;c+=256){ float s=f1g[c]/sqrtf(f1v[c]+EPSI); P[1312+c]=s; P[1376+c]=f1b[c]-f1m[c]*s; }
  const float *f2g=a.p[35],*f2b=a.p[36],*f2m=a.p[37],*f2v=a.p[38];
  for (int c=t;c<64;c+=256){ float s=f2g[c]/sqrtf(f2v[c]+EPSI); P[1440+c]=s; P[1504+c]=f2b[c]-f2m[c]*s; }
}

// ---------------- quantize + mode-pool(11,1,1) + fused 3->32->32 MLP ----------------
__global__ __launch_bounds__(256) void k_mode_mlp(const float* __restrict__ x,
                                                 const float* __restrict__ P,
                                                 float* __restrict__ dout) {
  __shared__ int qs[3*676];  // 3 channels, 26x26 levels
  int lx = threadIdx.x, ly = threadIdx.y;
  int tid = ly*16 + lx;
  int tx0 = blockIdx.x*16, ty0 = blockIdx.y*16;
  int b = blockIdx.z;
  for (int k = tid; k < 3*676; k += 256) {
    int cch = k/676; int rem = k - cch*676; int r = rem/26; int cc = rem - r*26;
    int gy = ty0 + r - 1, gx = tx0 + cc - 1;
    int q = 0;
    if ((unsigned)gy < 256u && (unsigned)gx < 256u) {
      float v = x[((size_t)(b*3+cch)*256 + gy)*256 + gx];
      q = (int)rintf(v*255.0f/16.0f);
      q = q < 0 ? 0 : (q > 16 ? 16 : q);
    }
    qs[k] = q;
  }
  __syncthreads();
  int oi = ty0 + ly, oj = tx0 + lx;
  if (oi >= 248 || oj >= 248) return;

  float md[3];
  #pragma unroll
  for (int cch = 0; cch < 3; cch++) {
    const int* qp = &qs[cch*676 + ly*26 + lx];
    unsigned h0=0,h1=0,h2=0,h3=0,h4=0;
    #pragma unroll 1
    for (int u = 0; u < 11; u++) {
      #pragma unroll
      for (int v = 0; v < 11; v++) {
        int q = qp[u*26 + v];
        unsigned inc = 1u << ((q & 3) << 3);
        int sel = q >> 2;
        h0 += (sel==0) ? inc : 0u;
        h1 += (sel==1) ? inc : 0u;
        h2 += (sel==2) ? inc : 0u;
        h3 += (sel==3) ? inc : 0u;
        h4 += (sel==4) ? inc : 0u;
      }
    }
    int best = -1, mode = 0;
    #define CHK(l, w) { int cnt = (int)((w >> (((l)&3)*8)) & 255u); if (cnt > best) { best = cnt; mode = (l); } }
    CHK(0,h0) CHK(1,h0) CHK(2,h0) CHK(3,h0)
    CHK(4,h1) CHK(5,h1) CHK(6,h1) CHK(7,h1)
    CHK(8,h2) CHK(9,h2) CHK(10,h2) CHK(11,h2)
    CHK(12,h3) CHK(13,h3) CHK(14,h3) CHK(15,h3)
    CHK(16,h4)
    #undef CHK
    md[cch] = (float)mode * 0.0625f;
  }

  const float* A1 = P;           const float* C1 = P + 96;
  const float* A2 = P + 128;     const float* C2 = P + 1152;
  float h[32];
  #pragma unroll
  for (int o = 0; o < 32; o++) {
    float v = C1[o] + A1[o*3]*md[0] + A1[o*3+1]*md[1] + A1[o*3+2]*md[2];
    h[o] = (v >= 0.f) ? v : 0.01f*v;
  }
  size_t ob = ((size_t)(b*32)*248 + oi)*248 + oj;
  #pragma unroll
  for (int o2 = 0; o2 < 32; o2++) {
    float acc = C2[o2];
    #pragma unroll
    for (int o = 0; o < 32; o++) acc += A2[o2*32+o]*h[o];
    acc = (acc >= 0.f) ? acc : 0.01f*acc;
    dout[ob + (size_t)o2*(248*248)] = acc;
  }
}

// ---------------- shared 3x3 conv, stride 3, pad 1 (248 -> 83) ----------------
__global__ void k_down(const float* __restrict__ in, float* __restrict__ out,
                       const float* __restrict__ scw, const float* __restrict__ scb) {
  const int Hin = 248, Hout = 83, total = 128*83*83;
  int idx = blockIdx.x*256 + threadIdx.x;
  if (idx >= total) return;
  float w[9];
  #pragma unroll
  for (int i = 0; i < 9; i++) w[i] = rfl(scw[i]);
  float bias = rfl(scb[0]);
  int j = idx % Hout; int t2 = idx / Hout; int i = t2 % Hout; int p = t2 / Hout;
  const float* base = in + (size_t)p*Hin*Hin;
  float s = bias;
  #pragma unroll
  for (int u = 0; u < 3; u++) {
    int r = 3*i - 1 + u;
    if ((unsigned)r < (unsigned)Hin) {
      #pragma unroll
      for (int v = 0; v < 3; v++) {
        int cc = 3*j - 1 + v;
        if ((unsigned)cc < (unsigned)Hin) s += base[(size_t)r*Hin + cc]*w[u*3+v];
      }
    }
  }
  out[idx] = s;
}

// ---------------- merged tail downsamples: 83->28->10->4->2, one block per (b,c) ----------------
__global__ __launch_bounds__(256) void k_down_rest(const float* __restrict__ in, float* __restrict__ ws,
                                                   const float* __restrict__ scw, const float* __restrict__ scb) {
  __shared__ float buf[6889 + 784 + 100 + 16];   // 31.2 KB
  int tid = threadIdx.x; int p = blockIdx.x;     // 128 blocks
  float w[9];
  #pragma unroll
  for (int i = 0; i < 9; i++) w[i] = rfl(scw[i]);
  float bias = rfl(scb[0]);
  const float* src = in + (size_t)p*6889;
  for (int k = tid; k < 6889; k += 256) buf[k] = src[k];
  __syncthreads();
  const int HIN[4] = {83,28,10,4}, HOUT[4] = {28,10,4,2};
  const int OIN[4] = {0, 6889, 6889+784, 6889+784+100};
  const size_t GOFF[4] = {P_D2, P_D3, P_D4, P_D5};
  #pragma unroll
  for (int st = 0; st < 4; st++) {
    const int hin = HIN[st], hout = HOUT[st];
    const float* bi = buf + OIN[st];
    float* bo = buf + OIN[st] + hin*hin;
    float* go = ws + GOFF[st] + (size_t)p*(hout*hout);
    for (int k = tid; k < hout*hout; k += 256) {
      int i = k/hout, j = k - i*hout;
      float s = bias;
      #pragma unroll
      for (int u = 0; u < 3; u++) {
        int r = 3*i - 1 + u;
        if ((unsigned)r < (unsigned)hin) {
          #pragma unroll
          for (int v = 0; v < 3; v++) {
            int cc = 3*j - 1 + v;
            if ((unsigned)cc < (unsigned)hin) s += bi[r*hin + cc]*w[u*3+v];
          }
        }
      }
      bo[k] = s; go[k] = s;
    }
    __syncthreads();
  }
}

// ---------------- pyramid: branch-split, 4x4 outputs/thread, NON-UNROLLED level loops ----------------
// Per-level constants bit-packed into scalars (no indexed const arrays -> no scratch);
// level base offset kept as running sum. Shrinks code + live ranges so the allocator
// can fit <=128 VGPR (4 waves/SIMD) — R8's fully-unrolled loops landed at 132 (3 waves).
#define NSP_PACK (83u | (28u<<7) | (10u<<14) | (4u<<21) | (2u<<28))
#define ROW_PACK (0u | (14u<<6) | (21u<<12) | (25u<<18) | (28u<<24))
__global__ __launch_bounds__(256) void k_accum(const float* __restrict__ ws,
                                               const float* __restrict__ iaw,
                                               const float* __restrict__ ibw,
                                               float* __restrict__ score) {
  __shared__ __align__(16) float hrow[3072];  // 30 rows x 96 + 2 zero rows x 96
  int tid = threadIdx.x;
  int c = blockIdx.y, b = blockIdx.z;
  int tx0 = (blockIdx.x & 3)*64, ty0 = (blockIdx.x >> 2)*32;
  int half = tid >> 7;                         // 0 = branch A, 1 = branch B
  int t2 = tid & 127;
  int lx4 = (t2 & 15)*4, lyt = t2 >> 4;        // 16x8 threads, 4w x 4h px each

  const float* wp = half ? ibw : iaw;
  float w[25];
  #pragma unroll
  for (int i = 0; i < 25; i++) w[i] = rfl(wp[i]);
  float s_ = rfl(ws[1184 + half*64 + c]);
  float C_ = rfl(ws[1216 + half*64 + c]);

  const int ZROW = 30*96;

  // ---- staging: x-lerped rows for all 5 levels + zero rows, ONE barrier ----
  for (int k = tid; k < 192; k += 256) hrow[ZROW + k] = 0.f;
  {
    size_t off = P_D1;
    #pragma unroll 1
    for (int lvl = 0; lvl < 5; lvl++) {
      const int n = (int)((NSP_PACK >> (7*lvl)) & 127u);
      const int hb = (int)((ROW_PACK >> (6*lvl)) & 63u) * 96;
      const float inv = (float)n * (1.f/256.f);
      float f0 = ((float)(ty0-2)+0.5f)*inv - 0.5f;
      float f1 = ((float)(ty0+33)+0.5f)*inv - 0.5f;
      int yb0 = min(max((int)floorf(f0),0), n-2);
      int yb1 = min(max((int)floorf(f1),0), n-2);
      int rows = yb1 - yb0 + 2;
      const float* dp = ws + off + (size_t)(b*32+c)*(n*n);
      #pragma unroll 1
      for (int k = tid; k < rows*68; k += 256) {
        int r = k/68, zx = k - r*68;
        int gx = tx0 + zx - 2;
        float h = 0.f;
        if ((unsigned)gx < 256u) {
          float f = ((float)gx + 0.5f)*inv - 0.5f;
          float ff = floorf(f);
          int i0 = (int)ff;
          int xb = min(max(i0,0), n-2);
          float wx = (i0 < 0) ? 0.f : (i0 > n-2 ? 1.f : f - ff);
          const float* rp = dp + (yb0 + r)*n + xb;
          h = rp[0] + wx*(rp[1] - rp[0]);
        }
        hrow[hb + r*96 + ((r&3)<<3) + zx] = h;   // bank-rotated row
      }
      off += (size_t)128*n*n;
    }
  }
  __syncthreads();                             // the ONLY barrier

  // ---- compute: 16 outputs/thread, one branch, level loop NOT unrolled ----
  float acc[16];
  #pragma unroll
  for (int i = 0; i < 16; i++) acc[i] = 0.f;
  int gy0 = ty0 + 4*lyt - 2;
  #pragma unroll 1
  for (int lvl = 0; lvl < 5; lvl++) {
    const int n = (int)((NSP_PACK >> (7*lvl)) & 127u);
    const int hb = (int)((ROW_PACK >> (6*lvl)) & 63u) * 96;
    const float inv = (float)n * (1.f/256.f);
    float f0u = ((float)(ty0-2)+0.5f)*inv - 0.5f;
    int yb0 = min(max((int)floorf(f0u),0), n-2);         // uniform -> SGPR
    float cc[4][4];
    #pragma unroll
    for (int p = 0; p < 4; p++)
      #pragma unroll
      for (int j = 0; j < 4; j++) cc[p][j] = 0.f;
    #pragma unroll
    for (int zr = 0; zr < 8; zr++) {
      int gy = gy0 + zr;
      float f = ((float)gy + 0.5f)*inv - 0.5f;
      float ff = floorf(f);
      int i0 = (int)ff;
      int yb = min(max(i0,0), n-2);
      float wy = (i0 < 0) ? 0.f : (i0 > n-2 ? 1.f : f - ff);
      bool valid = ((unsigned)gy < 256u);
      int r0 = yb - yb0;
      int offa = hb + r0*96 + ((r0&3)<<3) + lx4;
      int offb = hb + (r0+1)*96 + (((r0+1)&3)<<3) + lx4;
      offa = valid ? offa : (ZROW + lx4);
      offb = valid ? offb : (ZROW + 96 + lx4);
      wy = valid ? wy : 0.f;
      float4 a0 = *(const float4*)&hrow[offa];
      float4 a1 = *(const float4*)&hrow[offa+4];
      float4 b0 = *(const float4*)&hrow[offb];
      float4 b1 = *(const float4*)&hrow[offb+4];
      float z[8];
      z[0] = a0.x + wy*(b0.x - a0.x);
      z[1] = a0.y + wy*(b0.y - a0.y);
      z[2] = a0.z + wy*(b0.z - a0.z);
      z[3] = a0.w + wy*(b0.w - a0.w);
      z[4] = a1.x + wy*(b1.x - a1.x);
      z[5] = a1.y + wy*(b1.y - a1.y);
      z[6] = a1.z + wy*(b1.z - a1.z);
      z[7] = a1.w + wy*(b1.w - a1.w);
      #pragma unroll
      for (int p = 0; p < 4; p++) {
        int r = zr - p;
        if (r >= 0 && r < 5) {
          #pragma unroll
          for (int j = 0; j < 4; j++)
            #pragma unroll
            for (int v = 0; v < 5; v++)
              cc[p][j] += z[j+v]*w[r*5+v];
        }
      }
    }
    #pragma unroll
    for (int p = 0; p < 4; p++)
      #pragma unroll
      for (int j = 0; j < 4; j++) {
        float v = cc[p][j]*s_ + C_;
        acc[p*4+j] += (v >= 0.f) ? v : 0.01f*v;
      }
  }
  int oy = ty0 + 4*lyt, ox = tx0 + lx4;
  size_t base = ((size_t)(b*64 + half*32 + c)*256 + oy)*256 + ox;
  #pragma unroll
  for (int p = 0; p < 4; p++)
    *(float4*)&score[base + (size_t)p*256] = make_float4(acc[p*4],acc[p*4+1],acc[p*4+2],acc[p*4+3]);
}

// ---------------- ft pass: BN -> MaxLeakyReLU -> BN -> EmphaseLocal ----------------
__global__ __launch_bounds__(256) void k_ft(const float* __restrict__ in,
                                            float* __restrict__ out,
                                            const float* __restrict__ P, float scale) {
  __shared__ float A[74*77];   // pointwise(y) with halo 5; stride 77 (conflict fix)
  __shared__ float Bf[64*77];  // vertical 11-sums
  int tid = threadIdx.x;
  int c = blockIdx.y, b = blockIdx.z;
  int ty0 = (blockIdx.x >> 2)*64, tx0 = (blockIdx.x & 3)*64;
  float fs1 = rfl(P[1312+c]), fc1 = rfl(P[1376+c]), fs2 = rfl(P[1440+c]), fc2 = rfl(P[1504+c]);
  const float* ip = in + (size_t)(b*64 + c)*65536;
  for (int k = tid; k < 1480; k += 256) {        // 74 rows x 20 aligned float4
    int ay = k/20, qx = k - ay*20;
    int gy = ty0 + ay - 5;
    int gx0 = tx0 - 8 + qx*4;
    float4 v = make_float4(0.f,0.f,0.f,0.f);
    bool rowok = ((unsigned)gy < 256u);
    if (rowok) {
      if (gx0 >= 0 && gx0 <= 252) v = *(const float4*)(ip + gy*256 + gx0);
      else {
        float* pv = (float*)&v;
        #pragma unroll
        for (int e = 0; e < 4; e++) { int gx = gx0+e; if ((unsigned)gx < 256u) pv[e] = ip[gy*256 + gx]; }
      }
    }
    float* pv = (float*)&v;
    int ax0 = gx0 - tx0 + 5;
    #pragma unroll
    for (int e = 0; e < 4; e++) {
      int ax = ax0 + e;
      if ((unsigned)ax < 74u) {
        int gx = gx0 + e;
        float y = 0.f;
        if (rowok && (unsigned)gx < 256u) {
          float t = pv[e]*fs1 + fc1;
          t = (t > 0.1f) ? t : 0.7f*t;
          y = t*fs2 + fc2;
        }
        A[ay*77 + ax] = y;
      }
    }
  }
  __syncthreads();
  for (int task = tid; task < 296; task += 256) {   // 74 cols x 4 chunks of 16 rows
    int chunk = task/74; int col = task - chunk*74;
    int r0 = chunk*16;
    float s = 0.f;
    #pragma unroll
    for (int u = 0; u < 11; u++) s += A[(r0+u)*77 + col];
    Bf[r0*77 + col] = s;
    #pragma unroll
    for (int r = 1; r < 16; r++) {
      s += A[(r0+r+10)*77 + col] - A[(r0+r-1)*77 + col];
      Bf[(r0+r)*77 + col] = s;
    }
  }
  __syncthreads();
  {
    int r = tid >> 2; int c0 = (tid & 3)*16;        // 64 rows x 4 chunks of 16 cols
    float s = 0.f;
    #pragma unroll
    for (int v = 0; v < 11; v++) s += Bf[r*77 + c0 + v];
    float* op = out + (size_t)(b*64 + c)*65536 + (size_t)(ty0+r)*256 + tx0;
    float4 bufv;
    #pragma unroll
    for (int j = 0; j < 16; j++) {
      float mean = s*(1.f/121.f);
      float y = A[(r+5)*77 + c0 + j + 5];
      float sig = 1.f/(1.f + __expf(-(y - mean)));
      ((float*)&bufv)[j & 3] = y*sig*scale;
      if ((j & 3) == 3) *(float4*)(op + c0 + (j & ~3)) = bufv;
      if (j < 15) s += Bf[r*77 + c0 + j + 11] - Bf[r*77 + c0 + j];
    }
  }
}

// ---------------- launch ----------------
extern "C" void kernel_launch(void* const* d_in, const int* in_sizes, int n_in,
                              void* d_out, int out_size, void* d_ws, size_t ws_size,
                              hipStream_t stream) {
  const float* x = (const float*)d_in[0];
  float* ws = (float*)d_ws;
  float* out = (float*)d_out;

  PrepArgs pa;
  for (int i = 0; i < 39; i++) pa.p[i] = (const float*)d_in[i];
  k_prep<<<dim3(1), dim3(256), 0, stream>>>(pa, ws);

  k_mode_mlp<<<dim3(16,16,4), dim3(16,16), 0, stream>>>(x, ws, ws + P_D);

  const float* scw = (const float*)d_in[17];
  const float* scb = (const float*)d_in[18];
  {
    int total = 128*83*83;
    k_down<<<dim3((total+255)/256), dim3(256), 0, stream>>>(ws + P_D, ws + P_D1, scw, scb);
  }
  k_down_rest<<<dim3(128), dim3(256), 0, stream>>>(ws + P_D1, ws, scw, scb);

  k_accum<<<dim3(32,32,4), dim3(256), 0, stream>>>(ws, (const float*)d_in[19],
                                                   (const float*)d_in[25], ws + P_SCORE);

  // ft x3, ping-pong ws_score <-> d_out; /5 folded into last pass
  k_ft<<<dim3(16,64,4), dim3(256), 0, stream>>>(ws + P_SCORE, out, ws, 1.f);
  k_ft<<<dim3(16,64,4), dim3(256), 0, stream>>>(out, ws + P_SCORE, ws, 1.f);
  k_ft<<<dim3(16,64,4), dim3(256), 0, stream>>>(ws + P_SCORE, out, ws, 0.2f);
}

// Round 10
// 464.211 us; speedup vs baseline: 4.7394x; 1.0949x over previous
//
#include <hip/hip_runtime.h>
#include <math.h>

#define EPSI 1e-5f

// ---------------- workspace layout (floats) ----------------
//   A1[96] @0, C1[32] @96, A2[1024] @128, C2[32] @1152,
//   sa[32] @1184, Ca[32] @1216, sb[32] @1248, Cb[32] @1280,
//   fs1[64] @1312, fc1[64] @1376, fs2[64] @1440, fc2[64] @1504
#define P_D1 2048                    // 128*83*83 = 881792
#define P_D2 (P_D1 + 128*83*83)
#define P_D3 (P_D2 + 128*28*28)
#define P_D4 (P_D3 + 128*10*10)
#define P_D5 (P_D4 + 128*4*4)
#define P_SCORE (P_D5 + 128*2*2)     // 4*64*256*256 = 16777216 floats
#define P_D  P_SCORE                 // d (4,32,248,248) aliases score head (dead before accum)

__device__ __forceinline__ float rfl(float x) {
  return __builtin_bit_cast(float, __builtin_amdgcn_readfirstlane(__builtin_bit_cast(int, x)));
}

struct PrepArgs { const float* p[39]; };

// ---------------- prep: fold all affine params ----------------
__global__ void k_prep(PrepArgs a, float* __restrict__ P) {
  int t = threadIdx.x;
  const float *w1=a.p[1],*b1=a.p[2],*w2=a.p[3],*b2=a.p[4],*g1=a.p[5],*bb1=a.p[6],*m1=a.p[7],*v1=a.p[8];
  const float *w3=a.p[9],*b3=a.p[10],*w4=a.p[11],*b4=a.p[12],*g2=a.p[13],*bb2=a.p[14],*m2=a.p[15],*v2=a.p[16];
  for (int i=t;i<96;i+=256){ int o=i/3; float s=g1[o]/sqrtf(v1[o]+EPSI); P[i]=w1[i]*w2[o]*s; }
  for (int o=t;o<32;o+=256){ float s=g1[o]/sqrtf(v1[o]+EPSI); P[96+o]=(b1[o]*w2[o]+b2[o]-m1[o])*s+bb1[o]; }
  for (int i=t;i<1024;i+=256){ int o2=i/32; float s=g2[o2]/sqrtf(v2[o2]+EPSI); P[128+i]=w3[i]*w4[o2]*s; }
  for (int o=t;o<32;o+=256){ float s=g2[o]/sqrtf(v2[o]+EPSI); P[1152+o]=(b3[o]*w4[o]+b4[o]-m2[o])*s+bb2[o]; }
  const float *iag=a.p[21],*iab=a.p[22],*iam=a.p[23],*iav=a.p[24],*iabias=a.p[20];
  for (int c=t;c<32;c+=256){ float s=iag[c]/sqrtf(iav[c]+EPSI); P[1184+c]=s; P[1216+c]=(iabias[0]-iam[c])*s+iab[c]; }
  const float *ibg=a.p[27],*ibb=a.p[28],*ibm=a.p[29],*ibv=a.p[30],*ibbias=a.p[26];
  for (int c=t;c<32;c+=256){ float s=ibg[c]/sqrtf(ibv[c]+EPSI); P[1248+c]=s; P[1280+c]=(ibbias[0]-ibm[c])*s+ibb[c]; }
  const float *f1g=a.p[31],*f1b=a.p[32],*f1m=a.p[33],*f1v=a.p[34];
  for (int c=t;c<64;c+=256){ float s=f1g[c]/sqrtf(f1v[c]+EPSI); P[1312+c]=s; P[1376+c]=f1b[c]-f1m[c]*s; }
  const float *f2g=a.p[35],*f2b=a.p[36],*f2m=a.p[37],*f2v=a.p[38];
  for (int c=t;c<64;c+=256){ float s=f2g[c]/sqrtf(f2v[c]+EPSI); P[1440+c]=s; P[1504+c]=f2b[c]-f2m[c]*s; }
}

// ---------------- quantize + mode-pool(11,1,1) + fused 3->32->32 MLP ----------------
__global__ __launch_bounds__(256) void k_mode_mlp(const float* __restrict__ x,
                                                 const float* __restrict__ P,
                                                 float* __restrict__ dout) {
  __shared__ int qs[3*676];  // 3 channels, 26x26 levels
  int lx = threadIdx.x, ly = threadIdx.y;
  int tid = ly*16 + lx;
  int tx0 = blockIdx.x*16, ty0 = blockIdx.y*16;
  int b = blockIdx.z;
  for (int k = tid; k < 3*676; k += 256) {
    int cch = k/676; int rem = k - cch*676; int r = rem/26; int cc = rem - r*26;
    int gy = ty0 + r - 1, gx = tx0 + cc - 1;
    int q = 0;
    if ((unsigned)gy < 256u && (unsigned)gx < 256u) {
      float v = x[((size_t)(b*3+cch)*256 + gy)*256 + gx];
      q = (int)rintf(v*255.0f/16.0f);
      q = q < 0 ? 0 : (q > 16 ? 16 : q);
    }
    qs[k] = q;
  }
  __syncthreads();
  int oi = ty0 + ly, oj = tx0 + lx;
  if (oi >= 248 || oj >= 248) return;

  float md[3];
  #pragma unroll
  for (int cch = 0; cch < 3; cch++) {
    const int* qp = &qs[cch*676 + ly*26 + lx];
    unsigned h0=0,h1=0,h2=0,h3=0,h4=0;
    #pragma unroll 1
    for (int u = 0; u < 11; u++) {
      #pragma unroll
      for (int v = 0; v < 11; v++) {
        int q = qp[u*26 + v];
        unsigned inc = 1u << ((q & 3) << 3);
        int sel = q >> 2;
        h0 += (sel==0) ? inc : 0u;
        h1 += (sel==1) ? inc : 0u;
        h2 += (sel==2) ? inc : 0u;
        h3 += (sel==3) ? inc : 0u;
        h4 += (sel==4) ? inc : 0u;
      }
    }
    int best = -1, mode = 0;
    #define CHK(l, w) { int cnt = (int)((w >> (((l)&3)*8)) & 255u); if (cnt > best) { best = cnt; mode = (l); } }
    CHK(0,h0) CHK(1,h0) CHK(2,h0) CHK(3,h0)
    CHK(4,h1) CHK(5,h1) CHK(6,h1) CHK(7,h1)
    CHK(8,h2) CHK(9,h2) CHK(10,h2) CHK(11,h2)
    CHK(12,h3) CHK(13,h3) CHK(14,h3) CHK(15,h3)
    CHK(16,h4)
    #undef CHK
    md[cch] = (float)mode * 0.0625f;
  }

  const float* A1 = P;           const float* C1 = P + 96;
  const float* A2 = P + 128;     const float* C2 = P + 1152;
  float h[32];
  #pragma unroll
  for (int o = 0; o < 32; o++) {
    float v = C1[o] + A1[o*3]*md[0] + A1[o*3+1]*md[1] + A1[o*3+2]*md[2];
    h[o] = (v >= 0.f) ? v : 0.01f*v;
  }
  size_t ob = ((size_t)(b*32)*248 + oi)*248 + oj;
  #pragma unroll
  for (int o2 = 0; o2 < 32; o2++) {
    float acc = C2[o2];
    #pragma unroll
    for (int o = 0; o < 32; o++) acc += A2[o2*32+o]*h[o];
    acc = (acc >= 0.f) ? acc : 0.01f*acc;
    dout[ob + (size_t)o2*(248*248)] = acc;
  }
}

// ---------------- shared 3x3 conv, stride 3, pad 1 (248 -> 83) ----------------
__global__ void k_down(const float* __restrict__ in, float* __restrict__ out,
                       const float* __restrict__ scw, const float* __restrict__ scb) {
  const int Hin = 248, Hout = 83, total = 128*83*83;
  int idx = blockIdx.x*256 + threadIdx.x;
  if (idx >= total) return;
  float w[9];
  #pragma unroll
  for (int i = 0; i < 9; i++) w[i] = rfl(scw[i]);
  float bias = rfl(scb[0]);
  int j = idx % Hout; int t2 = idx / Hout; int i = t2 % Hout; int p = t2 / Hout;
  const float* base = in + (size_t)p*Hin*Hin;
  float s = bias;
  #pragma unroll
  for (int u = 0; u < 3; u++) {
    int r = 3*i - 1 + u;
    if ((unsigned)r < (unsigned)Hin) {
      #pragma unroll
      for (int v = 0; v < 3; v++) {
        int cc = 3*j - 1 + v;
        if ((unsigned)cc < (unsigned)Hin) s += base[(size_t)r*Hin + cc]*w[u*3+v];
      }
    }
  }
  out[idx] = s;
}

// ---------------- merged tail downsamples: 83->28->10->4->2, one block per (b,c) ----------------
__global__ __launch_bounds__(256) void k_down_rest(const float* __restrict__ in, float* __restrict__ ws,
                                                   const float* __restrict__ scw, const float* __restrict__ scb) {
  __shared__ float buf[6889 + 784 + 100 + 16];   // 31.2 KB
  int tid = threadIdx.x; int p = blockIdx.x;     // 128 blocks
  float w[9];
  #pragma unroll
  for (int i = 0; i < 9; i++) w[i] = rfl(scw[i]);
  float bias = rfl(scb[0]);
  const float* src = in + (size_t)p*6889;
  for (int k = tid; k < 6889; k += 256) buf[k] = src[k];
  __syncthreads();
  const int HIN[4] = {83,28,10,4}, HOUT[4] = {28,10,4,2};
  const int OIN[4] = {0, 6889, 6889+784, 6889+784+100};
  const size_t GOFF[4] = {P_D2, P_D3, P_D4, P_D5};
  #pragma unroll
  for (int st = 0; st < 4; st++) {
    const int hin = HIN[st], hout = HOUT[st];
    const float* bi = buf + OIN[st];
    float* bo = buf + OIN[st] + hin*hin;
    float* go = ws + GOFF[st] + (size_t)p*(hout*hout);
    for (int k = tid; k < hout*hout; k += 256) {
      int i = k/hout, j = k - i*hout;
      float s = bias;
      #pragma unroll
      for (int u = 0; u < 3; u++) {
        int r = 3*i - 1 + u;
        if ((unsigned)r < (unsigned)hin) {
          #pragma unroll
          for (int v = 0; v < 3; v++) {
            int cc = 3*j - 1 + v;
            if ((unsigned)cc < (unsigned)hin) s += bi[r*hin + cc]*w[u*3+v];
          }
        }
      }
      bo[k] = s; go[k] = s;
    }
    __syncthreads();
  }
}

// ---------------- pyramid: branch-split, 4x4 outputs/thread, NON-UNROLLED level loops ----------------
#define NSP_PACK (83u | (28u<<7) | (10u<<14) | (4u<<21) | (2u<<28))
#define ROW_PACK (0u | (14u<<6) | (21u<<12) | (25u<<18) | (28u<<24))
__global__ __launch_bounds__(256) void k_accum(const float* __restrict__ ws,
                                               const float* __restrict__ iaw,
                                               const float* __restrict__ ibw,
                                               float* __restrict__ score) {
  __shared__ __align__(16) float hrow[3072];  // 30 rows x 96 + 2 zero rows x 96
  int tid = threadIdx.x;
  int c = blockIdx.y, b = blockIdx.z;
  int tx0 = (blockIdx.x & 3)*64, ty0 = (blockIdx.x >> 2)*32;
  int half = tid >> 7;                         // 0 = branch A, 1 = branch B
  int t2 = tid & 127;
  int lx4 = (t2 & 15)*4, lyt = t2 >> 4;        // 16x8 threads, 4w x 4h px each

  const float* wp = half ? ibw : iaw;
  float w[25];
  #pragma unroll
  for (int i = 0; i < 25; i++) w[i] = rfl(wp[i]);
  float s_ = rfl(ws[1184 + half*64 + c]);
  float C_ = rfl(ws[1216 + half*64 + c]);

  const int ZROW = 30*96;

  // ---- staging: x-lerped rows for all 5 levels + zero rows, ONE barrier ----
  for (int k = tid; k < 192; k += 256) hrow[ZROW + k] = 0.f;
  {
    size_t off = P_D1;
    #pragma unroll 1
    for (int lvl = 0; lvl < 5; lvl++) {
      const int n = (int)((NSP_PACK >> (7*lvl)) & 127u);
      const int hb = (int)((ROW_PACK >> (6*lvl)) & 63u) * 96;
      const float inv = (float)n * (1.f/256.f);
      float f0 = ((float)(ty0-2)+0.5f)*inv - 0.5f;
      float f1 = ((float)(ty0+33)+0.5f)*inv - 0.5f;
      int yb0 = min(max((int)floorf(f0),0), n-2);
      int yb1 = min(max((int)floorf(f1),0), n-2);
      int rows = yb1 - yb0 + 2;
      const float* dp = ws + off + (size_t)(b*32+c)*(n*n);
      #pragma unroll 1
      for (int k = tid; k < rows*68; k += 256) {
        int r = k/68, zx = k - r*68;
        int gx = tx0 + zx - 2;
        float h = 0.f;
        if ((unsigned)gx < 256u) {
          float f = ((float)gx + 0.5f)*inv - 0.5f;
          float ff = floorf(f);
          int i0 = (int)ff;
          int xb = min(max(i0,0), n-2);
          float wx = (i0 < 0) ? 0.f : (i0 > n-2 ? 1.f : f - ff);
          const float* rp = dp + (yb0 + r)*n + xb;
          h = rp[0] + wx*(rp[1] - rp[0]);
        }
        hrow[hb + r*96 + ((r&3)<<3) + zx] = h;   // bank-rotated row
      }
      off += (size_t)128*n*n;
    }
  }
  __syncthreads();                             // the ONLY barrier

  // ---- compute: 16 outputs/thread, one branch, level loop NOT unrolled ----
  float acc[16];
  #pragma unroll
  for (int i = 0; i < 16; i++) acc[i] = 0.f;
  int gy0 = ty0 + 4*lyt - 2;
  #pragma unroll 1
  for (int lvl = 0; lvl < 5; lvl++) {
    const int n = (int)((NSP_PACK >> (7*lvl)) & 127u);
    const int hb = (int)((ROW_PACK >> (6*lvl)) & 63u) * 96;
    const float inv = (float)n * (1.f/256.f);
    float f0u = ((float)(ty0-2)+0.5f)*inv - 0.5f;
    int yb0 = min(max((int)floorf(f0u),0), n-2);         // uniform -> SGPR
    float cc[4][4];
    #pragma unroll
    for (int p = 0; p < 4; p++)
      #pragma unroll
      for (int j = 0; j < 4; j++) cc[p][j] = 0.f;
    #pragma unroll
    for (int zr = 0; zr < 8; zr++) {
      int gy = gy0 + zr;
      float f = ((float)gy + 0.5f)*inv - 0.5f;
      float ff = floorf(f);
      int i0 = (int)ff;
      int yb = min(max(i0,0), n-2);
      float wy = (i0 < 0) ? 0.f : (i0 > n-2 ? 1.f : f - ff);
      bool valid = ((unsigned)gy < 256u);
      int r0 = yb - yb0;
      int offa = hb + r0*96 + ((r0&3)<<3) + lx4;
      int offb = hb + (r0+1)*96 + (((r0+1)&3)<<3) + lx4;
      offa = valid ? offa : (ZROW + lx4);
      offb = valid ? offb : (ZROW + 96 + lx4);
      wy = valid ? wy : 0.f;
      float4 a0 = *(const float4*)&hrow[offa];
      float4 a1 = *(const float4*)&hrow[offa+4];
      float4 b0 = *(const float4*)&hrow[offb];
      float4 b1 = *(const float4*)&hrow[offb+4];
      float z[8];
      z[0] = a0.x + wy*(b0.x - a0.x);
      z[1] = a0.y + wy*(b0.y - a0.y);
      z[2] = a0.z + wy*(b0.z - a0.z);
      z[3] = a0.w + wy*(b0.w - a0.w);
      z[4] = a1.x + wy*(b1.x - a1.x);
      z[5] = a1.y + wy*(b1.y - a1.y);
      z[6] = a1.z + wy*(b1.z - a1.z);
      z[7] = a1.w + wy*(b1.w - a1.w);
      #pragma unroll
      for (int p = 0; p < 4; p++) {
        int r = zr - p;
        if (r >= 0 && r < 5) {
          #pragma unroll
          for (int j = 0; j < 4; j++)
            #pragma unroll
            for (int v = 0; v < 5; v++)
              cc[p][j] += z[j+v]*w[r*5+v];
        }
      }
    }
    #pragma unroll
    for (int p = 0; p < 4; p++)
      #pragma unroll
      for (int j = 0; j < 4; j++) {
        float v = cc[p][j]*s_ + C_;
        acc[p*4+j] += (v >= 0.f) ? v : 0.01f*v;
      }
  }
  int oy = ty0 + 4*lyt, ox = tx0 + lx4;
  size_t base = ((size_t)(b*64 + half*32 + c)*256 + oy)*256 + ox;
  #pragma unroll
  for (int p = 0; p < 4; p++)
    *(float4*)&score[base + (size_t)p*256] = make_float4(acc[p*4],acc[p*4+1],acc[p*4+2],acc[p*4+3]);
}

// ---------------- ft pass: BN -> MaxLeakyReLU -> BN -> EmphaseLocal ----------------
// Tile 64(w) x 32(h): LDS 22.8 KB (was 42.6) -> ~7 blocks/CU by LDS, grid 8192.
// Same math; doubles resident waves to hide the LDS-chain latency.
__global__ __launch_bounds__(256) void k_ft(const float* __restrict__ in,
                                            float* __restrict__ out,
                                            const float* __restrict__ P, float scale) {
  __shared__ float A[42*77];   // pointwise(y), rows ty0-5..ty0+36, cols tx0-5..tx0+68
  __shared__ float Bf[32*77];  // vertical 11-sums
  int tid = threadIdx.x;
  int c = blockIdx.y, b = blockIdx.z;
  int ty0 = (blockIdx.x >> 2)*32, tx0 = (blockIdx.x & 3)*64;
  float fs1 = rfl(P[1312+c]), fc1 = rfl(P[1376+c]), fs2 = rfl(P[1440+c]), fc2 = rfl(P[1504+c]);
  const float* ip = in + (size_t)(b*64 + c)*65536;
  for (int k = tid; k < 840; k += 256) {         // 42 rows x 20 aligned float4
    int ay = k/20, qx = k - ay*20;
    int gy = ty0 + ay - 5;
    int gx0 = tx0 - 8 + qx*4;
    float4 v = make_float4(0.f,0.f,0.f,0.f);
    bool rowok = ((unsigned)gy < 256u);
    if (rowok) {
      if (gx0 >= 0 && gx0 <= 252) v = *(const float4*)(ip + gy*256 + gx0);
      else {
        float* pv = (float*)&v;
        #pragma unroll
        for (int e = 0; e < 4; e++) { int gx = gx0+e; if ((unsigned)gx < 256u) pv[e] = ip[gy*256 + gx]; }
      }
    }
    float* pv = (float*)&v;
    int ax0 = gx0 - tx0 + 5;
    #pragma unroll
    for (int e = 0; e < 4; e++) {
      int ax = ax0 + e;
      if ((unsigned)ax < 74u) {
        int gx = gx0 + e;
        float y = 0.f;
        if (rowok && (unsigned)gx < 256u) {
          float t = pv[e]*fs1 + fc1;
          t = (t > 0.1f) ? t : 0.7f*t;
          y = t*fs2 + fc2;
        }
        A[ay*77 + ax] = y;
      }
    }
  }
  __syncthreads();
  for (int task = tid; task < 148; task += 256) {   // 74 cols x 2 chunks of 16 rows
    int chunk = task/74; int col = task - chunk*74;
    int r0 = chunk*16;
    float s = 0.f;
    #pragma unroll
    for (int u = 0; u < 11; u++) s += A[(r0+u)*77 + col];
    Bf[r0*77 + col] = s;
    #pragma unroll
    for (int r = 1; r < 16; r++) {
      s += A[(r0+r+10)*77 + col] - A[(r0+r-1)*77 + col];
      Bf[(r0+r)*77 + col] = s;
    }
  }
  __syncthreads();
  {
    int r = tid >> 3; int c0 = (tid & 7)*8;        // 32 rows x 8 chunks of 8 cols
    float s = 0.f;
    #pragma unroll
    for (int v = 0; v < 11; v++) s += Bf[r*77 + c0 + v];
    float* op = out + (size_t)(b*64 + c)*65536 + (size_t)(ty0+r)*256 + tx0;
    float4 bufv;
    #pragma unroll
    for (int j = 0; j < 8; j++) {
      float mean = s*(1.f/121.f);
      float y = A[(r+5)*77 + c0 + j + 5];
      float sig = 1.f/(1.f + __expf(-(y - mean)));
      ((float*)&bufv)[j & 3] = y*sig*scale;
      if ((j & 3) == 3) *(float4*)(op + c0 + (j & ~3)) = bufv;
      if (j < 7) s += Bf[r*77 + c0 + j + 11] - Bf[r*77 + c0 + j];
    }
  }
}

// ---------------- launch ----------------
extern "C" void kernel_launch(void* const* d_in, const int* in_sizes, int n_in,
                              void* d_out, int out_size, void* d_ws, size_t ws_size,
                              hipStream_t stream) {
  const float* x = (const float*)d_in[0];
  float* ws = (float*)d_ws;
  float* out = (float*)d_out;

  PrepArgs pa;
  for (int i = 0; i < 39; i++) pa.p[i] = (const float*)d_in[i];
  k_prep<<<dim3(1), dim3(256), 0, stream>>>(pa, ws);

  k_mode_mlp<<<dim3(16,16,4), dim3(16,16), 0, stream>>>(x, ws, ws + P_D);

  const float* scw = (const float*)d_in[17];
  const float* scb = (const float*)d_in[18];
  {
    int total = 128*83*83;
    k_down<<<dim3((total+255)/256), dim3(256), 0, stream>>>(ws + P_D, ws + P_D1, scw, scb);
  }
  k_down_rest<<<dim3(128), dim3(256), 0, stream>>>(ws + P_D1, ws, scw, scb);

  k_accum<<<dim3(32,32,4), dim3(256), 0, stream>>>(ws, (const float*)d_in[19],
                                                   (const float*)d_in[25], ws + P_SCORE);

  // ft x3, ping-pong ws_score <-> d_out; /5 folded into last pass
  k_ft<<<dim3(32,64,4), dim3(256), 0, stream>>>(ws + P_SCORE, out, ws, 1.f);
  k_ft<<<dim3(32,64,4), dim3(256), 0, stream>>>(out, ws + P_SCORE, ws, 1.f);
  k_ft<<<dim3(32,64,4), dim3(256), 0, stream>>>(ws + P_SCORE, out, ws, 0.2f);
}